// Round 13
// baseline (750.230 us; speedup 1.0000x reference)
//
#include <hip/hip_runtime.h>
#include <hip/hip_bf16.h>
#include <math.h>

#define B_   128
#define L_   1024
#define E_   8
#define K_   3

typedef float f32x4 __attribute__((ext_vector_type(4)));
typedef short s8v  __attribute__((ext_vector_type(8)));
typedef unsigned short u16x8 __attribute__((ext_vector_type(8)));

__device__ inline ushort f2bf(float v) {
  union { float f; unsigned u; } x; x.f = v;
  unsigned r = (x.u + 0x7fffu + ((x.u >> 16) & 1u)) >> 16;
  return (ushort)r;
}
__device__ inline float bf2f(ushort h) {
  union { unsigned u; float f; } x; x.u = ((unsigned)h) << 16;
  return x.f;
}

// async global->LDS DMA, 16B/lane; dest linear in granule index.
__device__ __forceinline__ void gload_lds16(const ushort* g, ushort* l) {
  __builtin_amdgcn_global_load_lds(
      (const __attribute__((address_space(1))) unsigned int*)g,
      (__attribute__((address_space(3))) unsigned int*)l, 16, 0, 0);
}

// ---------------------------------------------------------------------------
// conv1: x[128,1,1024] -> h[128,16,1024] (ReLU) + pooled[128,16]
// ---------------------------------------------------------------------------
__global__ __launch_bounds__(256) void conv1_k(
    const float* __restrict__ x, const float* __restrict__ w,
    const float* __restrict__ bias, float* __restrict__ h,
    float* __restrict__ pooled)
{
  const int b = blockIdx.x;
  const int t = threadIdx.x;
  __shared__ float xs[1026];
  __shared__ float wsm[48];
  __shared__ float bs[16];
  __shared__ float red[4][16];

  for (int i = t; i < 1024; i += 256) xs[i + 1] = x[(size_t)b * 1024 + i];
  if (t == 0) { xs[0] = 0.f; xs[1025] = 0.f; }
  if (t < 48) wsm[t] = w[t];
  if (t < 16) bs[t] = bias[t];
  __syncthreads();

  float ps[16];
#pragma unroll
  for (int c = 0; c < 16; ++c) ps[c] = 0.f;

  for (int li = 0; li < 4; ++li) {
    const int l = t + li * 256;
    const float xm = xs[l], x0 = xs[l + 1], xp = xs[l + 2];
#pragma unroll
    for (int co = 0; co < 16; ++co) {
      float v = fmaf(wsm[co * 3 + 0], xm,
                fmaf(wsm[co * 3 + 1], x0,
                fmaf(wsm[co * 3 + 2], xp, bs[co])));
      v = fmaxf(v, 0.f);
      h[((size_t)b * 16 + co) * 1024 + l] = v;
      ps[co] += v;
    }
  }
#pragma unroll
  for (int co = 0; co < 16; ++co) {
    float v = ps[co];
    for (int off = 32; off > 0; off >>= 1) v += __shfl_down(v, off, 64);
    ps[co] = v;
  }
  const int wid = t >> 6, lane = t & 63;
  if (lane == 0) {
#pragma unroll
    for (int co = 0; co < 16; ++co) red[wid][co] = ps[co];
  }
  __syncthreads();
  if (t < 16) pooled[(size_t)b * 16 + t] =
      (red[0][t] + red[1][t] + red[2][t] + red[3][t]) * (1.f / 1024.f);
}

// ---------------------------------------------------------------------------
// router: pooled -> top3 gates + cv^2
// ---------------------------------------------------------------------------
__global__ void router_k(const float* __restrict__ pooled,
                         const float* __restrict__ rw,
                         const float* __restrict__ rb,
                         float* __restrict__ pair_g, int* __restrict__ pair_e,
                         float* __restrict__ cv2_out)
{
  const int b = threadIdx.x;  // 0..127
  __shared__ float pl[128][8];
  __shared__ float mp[8];

  float pv[16];
#pragma unroll
  for (int i = 0; i < 16; ++i) pv[i] = pooled[(size_t)b * 16 + i];

  float lg[8];
#pragma unroll
  for (int e = 0; e < 8; ++e) {
    float s = rb[e];
#pragma unroll
    for (int i = 0; i < 16; ++i) s = fmaf(pv[i], rw[e * 16 + i], s);
    lg[e] = s;
  }
  float mx = lg[0];
#pragma unroll
  for (int e = 1; e < 8; ++e) mx = fmaxf(mx, lg[e]);
  float pr[8]; float sum = 0.f;
#pragma unroll
  for (int e = 0; e < 8; ++e) { pr[e] = expf(lg[e] - mx); sum += pr[e]; }
  const float inv = 1.f / sum;
#pragma unroll
  for (int e = 0; e < 8; ++e) { pr[e] *= inv; pl[b][e] = pr[e]; }

  bool used[8] = {false,false,false,false,false,false,false,false};
  float tg[3]; int ti[3];
  for (int k = 0; k < 3; ++k) {
    float best = -1.f; int bi = 0;
#pragma unroll
    for (int e = 0; e < 8; ++e)
      if (!used[e] && pr[e] > best) { best = pr[e]; bi = e; }
    used[bi] = true; tg[k] = best; ti[k] = bi;
  }
  const float ts = 1.f / (tg[0] + tg[1] + tg[2]);
  for (int k = 0; k < 3; ++k) {
    pair_g[b * 3 + k] = tg[k] * ts;
    pair_e[b * 3 + k] = ti[k];
  }
  __syncthreads();
  if (b < 8) {
    float s = 0.f;
    for (int i = 0; i < 128; ++i) s += pl[i][b];
    mp[b] = s * (1.f / 128.f);
  }
  __syncthreads();
  if (b == 0) {
    float m = 0.f;
    for (int e = 0; e < 8; ++e) m += mp[e];
    m *= (1.f / 8.f);
    float v = 0.f;
    for (int e = 0; e < 8; ++e) { float d = mp[e] - m; v += d * d; }
    v *= (1.f / 7.f);
    const float cv = sqrtf(v) / (m + 1e-10f);
    cv2_out[0] = cv * cv;
  }
}

// ---------------------------------------------------------------------------
// Vector conv (e1, e2 only)
// ---------------------------------------------------------------------------
template <int CI, int CO, int LIN, bool POOL, int CIC, int CO_T, int CO_R,
          int IN_DIV>
__global__ __launch_bounds__(256) void convR_k(
    const float* __restrict__ in, const float* __restrict__ w,
    const float* __restrict__ bias, float* __restrict__ out,
    const int* __restrict__ pe)
{
  constexpr int CQ  = CO_T / CO_R;
  constexpr int LQ  = 256 / CQ;
  constexpr int L_T = LQ * 4;
  constexpr int LOUT = POOL ? (LIN / 2) : LIN;
  constexpr int RS  = L_T + 8;
  constexpr int CG  = CO_R / 4;

  const int p  = blockIdx.x;
  const int cb = blockIdx.y * CO_T;
  const int l0 = blockIdx.z * L_T;
  const int e  = pe ? pe[p] : 0;
  const float* inp = in + (size_t)(p / IN_DIV) * CI * LIN;
  const float* wp  = w + (size_t)e * CO * CI * 3;

  __shared__ float in_s[CIC * RS];
  __shared__ float w_s[CIC * 3 * CO_T];

  const int t  = threadIdx.x;
  const int cq = t / LQ;
  const int lq = t % LQ;

  float acc[CO_R][4];
#pragma unroll
  for (int c = 0; c < CO_R; ++c)
#pragma unroll
    for (int l = 0; l < 4; ++l) acc[c][l] = 0.f;

  for (int c0 = 0; c0 < CI; c0 += CIC) {
    for (int idx = t; idx < CIC * (L_T + 2); idx += 256) {
      const int ci = idx / (L_T + 2);
      const int j  = idx - ci * (L_T + 2);
      const int gl = l0 + j - 1;
      in_s[ci * RS + j] =
          (gl >= 0 && gl < LIN) ? inp[(size_t)(c0 + ci) * LIN + gl] : 0.f;
    }
    for (int i = t; i < CIC * CO_T; i += 256) {
      const int co = i % CO_T;
      const int ci = i / CO_T;
      const float* wsrc = wp + ((size_t)(cb + co) * CI + (c0 + ci)) * 3;
      const float w0 = wsrc[0], w1 = wsrc[1], w2 = wsrc[2];
      w_s[(ci * 3 + 0) * CO_T + co] = w0;
      w_s[(ci * 3 + 1) * CO_T + co] = w1;
      w_s[(ci * 3 + 2) * CO_T + co] = w2;
    }
    __syncthreads();
#pragma unroll 4
    for (int ci = 0; ci < CIC; ++ci) {
      const float* row = &in_s[ci * RS + lq * 4];
      const float4 xa = *reinterpret_cast<const float4*>(row);
      const float2 xb = *reinterpret_cast<const float2*>(row + 4);
      const float xv[6] = {xa.x, xa.y, xa.z, xa.w, xb.x, xb.y};
      const float* wrow = &w_s[ci * 3 * CO_T + cq * CO_R];
#pragma unroll
      for (int k = 0; k < 3; ++k) {
#pragma unroll
        for (int cg = 0; cg < CG; ++cg) {
          const float4 wv =
              *reinterpret_cast<const float4*>(&wrow[k * CO_T + cg * 4]);
          const float wq[4] = {wv.x, wv.y, wv.z, wv.w};
#pragma unroll
          for (int c = 0; c < 4; ++c)
#pragma unroll
            for (int l = 0; l < 4; ++l)
              acc[cg * 4 + c][l] = fmaf(wq[c], xv[l + k], acc[cg * 4 + c][l]);
        }
      }
    }
    __syncthreads();
  }

#pragma unroll
  for (int c = 0; c < CO_R; ++c) {
    const int co = cb + cq * CO_R + c;
    const float bv = bias[(size_t)e * CO + co];
    const float v0 = acc[c][0] + bv, v1 = acc[c][1] + bv;
    const float v2 = acc[c][2] + bv, v3 = acc[c][3] + bv;
    float* op = out + ((size_t)p * CO + co) * LOUT;
    if (POOL) {
      const int lo = (l0 >> 1) + lq * 2;
      float2 r;
      r.x = fmaxf(fmaxf(v0, v1), 0.f);
      r.y = fmaxf(fmaxf(v2, v3), 0.f);
      *reinterpret_cast<float2*>(&op[lo]) = r;
    } else {
      const int l = l0 + lq * 4;
      *reinterpret_cast<float4*>(&op[l]) = make_float4(v0, v1, v2, v3);
    }
  }
}

// ---------------------------------------------------------------------------
// Weight prep: w fp32 [E][CO][CI][3] -> hi/lo bf16 [E][3][CI/32][CO][32]
// ---------------------------------------------------------------------------
__global__ void wprep_k(const float* __restrict__ w, ushort* __restrict__ oh,
                        ushort* __restrict__ ol, int E, int CO, int CI,
                        int total)
{
  const int idx = blockIdx.x * 256 + threadIdx.x;
  if (idx >= total) return;
  const int KC = CI >> 5;
  const int j = idx & 31;
  int r = idx >> 5;
  const int co = r % CO; r /= CO;
  const int kc = r % KC; r /= KC;
  const int tp = r % 3;
  const int e  = r / 3;
  const float v = w[(((size_t)e * CO + co) * CI + (kc * 32 + j)) * 3 + tp];
  const ushort hi = f2bf(v);
  oh[idx] = hi;
  ol[idx] = f2bf(v - bf2f(hi));
}

// ---------------------------------------------------------------------------
// t0: e2 out fp32 [P][32][512] -> xt3 hi/lo bf16 [P][514][32] (halo rows 0)
// ---------------------------------------------------------------------------
__global__ __launch_bounds__(256) void t0_k(const float* __restrict__ in,
                                            ushort* __restrict__ oh,
                                            ushort* __restrict__ ol)
{
  __shared__ float tile[32][33];
  const int p  = blockIdx.x;
  const int l0 = blockIdx.y * 32;
  const int tx = threadIdx.x & 31;
  const int ty = threadIdx.x >> 5;

#pragma unroll
  for (int i = 0; i < 4; ++i) {
    const int ci = ty + i * 8;
    tile[ci][tx] = in[(size_t)p * 16384 + (size_t)ci * 512 + l0 + tx];
  }
  __syncthreads();
#pragma unroll
  for (int i = 0; i < 4; ++i) {
    const int l = l0 + ty + i * 8;
    const float v = tile[tx][ty + i * 8];
    const size_t o = ((size_t)p * 514 + 1 + l) * 32 + tx;
    const ushort hi = f2bf(v);
    oh[o] = hi;
    ol[o] = f2bf(v - bf2f(hi));
  }
  if (blockIdx.y == 0 && threadIdx.x < 32) {
    const size_t o0 = (size_t)p * 514 * 32 + threadIdx.x;
    const size_t o1 = ((size_t)p * 514 + 513) * 32 + threadIdx.x;
    oh[o0] = 0; ol[o0] = 0; oh[o1] = 0; ol[o1] = 0;
  }
}

// ---------------------------------------------------------------------------
// Old 16x16x32 MFMA conv, 32l x 64co wave tile (e3 only now).
// ---------------------------------------------------------------------------
template <int CI, int CO, int L, int OMODE>
__global__ __launch_bounds__(256) void convM_k(
    const ushort* __restrict__ xh, const ushort* __restrict__ xl,
    const ushort* __restrict__ wh, const ushort* __restrict__ wl,
    const float* __restrict__ bias,
    ushort* __restrict__ oh, ushort* __restrict__ ol,
    float* __restrict__ of,
    const int* __restrict__ pe, const float* __restrict__ pg,
    int pair0)
{
  constexpr int KC = CI / 32;
  const int bx = blockIdx.x;
  const int cb = blockIdx.y * 64;
  const int lz = blockIdx.z * 128;

  __shared__ ushort xs[2][130][32];
  __shared__ ushort wsm[2][3][64][32];
  ushort* xsf = &xs[0][0][0];
  ushort* wsf = &wsm[0][0][0][0];

  const int t = threadIdx.x;
  const int lane = t & 63;
  const int wv = t >> 6;
  const int l16 = lane & 15;
  const int kb8 = (lane >> 4) * 8;

  const int e = pe[pair0 + bx];
  const int lp = bx;

  f32x4 acc[2][4];
#pragma unroll
  for (int a = 0; a < 2; ++a)
#pragma unroll
    for (int b = 0; b < 4; ++b) acc[a][b] = (f32x4){0.f, 0.f, 0.f, 0.f};

  const size_t xbase = ((size_t)lp * (L + 2) + lz) * CI;

  for (int kc = 0; kc < KC; ++kc) {
    const int c0 = kc * 32;
#pragma unroll
    for (int it = 0; it < 5; ++it) {
      const int g = it * 256 + t;
      if (g < 1040) {
        const int pl = g >= 520;
        const int r = g - pl * 520;
        const int row = r >> 2;
        const int c16 = r & 3;
        const ushort* src =
            (pl ? xl : xh) + xbase + (size_t)row * CI + c0 + c16 * 8;
        gload_lds16(src, xsf + (size_t)g * 8);
      }
    }
#pragma unroll
    for (int it = 0; it < 6; ++it) {
      const int g = it * 256 + t;
      const int pl = g >= 768;
      const int r = g - pl * 768;
      const int tp = r >> 8;
      const int rr = r & 255;
      const int co = rr >> 2;
      const int c16 = rr & 3;
      const ushort* src = (pl ? wl : wh) +
          ((((size_t)e * 3 + tp) * KC + kc) * CO + cb + co) * 32 + c16 * 8;
      gload_lds16(src, wsf + (size_t)g * 8);
    }
    __syncthreads();

    __builtin_amdgcn_s_setprio(1);
#pragma unroll
    for (int tp = 0; tp < 3; ++tp) {
      const int ar = wv * 32 + l16 + tp;
      s8v a00 = *reinterpret_cast<const s8v*>(&xs[0][ar][kb8]);
      s8v a01 = *reinterpret_cast<const s8v*>(&xs[0][ar + 16][kb8]);
      s8v a10 = *reinterpret_cast<const s8v*>(&xs[1][ar][kb8]);
      s8v a11 = *reinterpret_cast<const s8v*>(&xs[1][ar + 16][kb8]);
#pragma unroll
      for (int cs = 0; cs < 4; ++cs) {
        const int brow = cs * 16 + l16;
        s8v bh = *reinterpret_cast<const s8v*>(&wsm[0][tp][brow][kb8]);
        s8v bl = *reinterpret_cast<const s8v*>(&wsm[1][tp][brow][kb8]);
        acc[0][cs] = __builtin_amdgcn_mfma_f32_16x16x32_bf16(a00, bh, acc[0][cs], 0, 0, 0);
        acc[0][cs] = __builtin_amdgcn_mfma_f32_16x16x32_bf16(a00, bl, acc[0][cs], 0, 0, 0);
        acc[0][cs] = __builtin_amdgcn_mfma_f32_16x16x32_bf16(a10, bh, acc[0][cs], 0, 0, 0);
        acc[1][cs] = __builtin_amdgcn_mfma_f32_16x16x32_bf16(a01, bh, acc[1][cs], 0, 0, 0);
        acc[1][cs] = __builtin_amdgcn_mfma_f32_16x16x32_bf16(a01, bl, acc[1][cs], 0, 0, 0);
        acc[1][cs] = __builtin_amdgcn_mfma_f32_16x16x32_bf16(a11, bh, acc[1][cs], 0, 0, 0);
      }
    }
    __builtin_amdgcn_s_setprio(0);
    __syncthreads();
  }

  float bv[4];
#pragma unroll
  for (int cs = 0; cs < 4; ++cs)
    bv[cs] = bias[(size_t)e * CO + cb + cs * 16 + l16];

  // OMODE 0 only (e3): plain conv -> bf16 hi/lo [NP][L+2][CO]
#pragma unroll
  for (int ls = 0; ls < 2; ++ls)
#pragma unroll
    for (int cs = 0; cs < 4; ++cs)
#pragma unroll
      for (int r = 0; r < 4; ++r) {
        const int l = lz + wv * 32 + ls * 16 + (lane >> 4) * 4 + r;
        const float v = acc[ls][cs][r] + bv[cs];
        const size_t o = ((size_t)lp * (L + 2) + 1 + l) * CO + cb + cs * 16 + l16;
        const ushort hi = f2bf(v);
        oh[o] = hi;
        ol[o] = f2bf(v - bf2f(hi));
      }
  if (blockIdx.z == 0 && t < 64) {
    const size_t o0 = (size_t)lp * (L + 2) * CO + cb + t;
    const size_t o1 = ((size_t)lp * (L + 2) + (L + 1)) * CO + cb + t;
    oh[o0] = 0; ol[o0] = 0; oh[o1] = 0; ol[o1] = 0;
  }
}

// ---------------------------------------------------------------------------
// convM2: 16x16x32 MFMA conv, 64l x 64co WAVE tile (48 LDS reads / 144
// MFMA-eq per kc per wave vs 72/144 for the 32lx64co tile -> LDS-read cap
// rises ~48%->~70%). Block = 4 waves = WL x WC of 64lx64co; block tile
// (WL*64) l x (WC*64) co. Proven 16x16 layouts unchanged.
// OMODEs as before.
// ---------------------------------------------------------------------------
template <int CI, int CO, int L, int OMODE, int WL, int WC>
__global__ __launch_bounds__(256) void convM2_k(
    const ushort* __restrict__ xh, const ushort* __restrict__ xl,
    const ushort* __restrict__ wh, const ushort* __restrict__ wl,
    const float* __restrict__ bias,
    ushort* __restrict__ oh, ushort* __restrict__ ol,
    float* __restrict__ of,
    const int* __restrict__ pe, const float* __restrict__ pg,
    int pair0)
{
  constexpr int KC = CI / 32;
  constexpr int NK = (OMODE == 1) ? 3 : 1;
  constexpr int LT = WL * 64;
  constexpr int CT = WC * 64;
  constexpr int XROWS = LT + 2;
  constexpr int XG = 2 * XROWS * 4;   // X granules (2 planes)
  constexpr int WG = 2 * 3 * CT * 4;  // W granules (2 planes x 3 taps)
  constexpr int XIT = (XG + 255) / 256;
  constexpr int WIT = (WG + 255) / 256;

  const int bx = blockIdx.x;
  const int cb = blockIdx.y * CT;
  const int lz = blockIdx.z * LT;

  __shared__ ushort xs[2][XROWS][32];
  __shared__ ushort wsm[2][3][CT][32];
  ushort* xsf = &xs[0][0][0];
  ushort* wsf = &wsm[0][0][0][0];

  const int t = threadIdx.x;
  const int lane = t & 63;
  const int wv = t >> 6;
  const int wvl = wv / WC;
  const int wvc = wv % WC;
  const int l16 = lane & 15;
  const int kb8 = (lane >> 4) * 8;

  float gacc[4][4][2];
  if (OMODE == 1) {
#pragma unroll
    for (int a = 0; a < 4; ++a)
#pragma unroll
      for (int b = 0; b < 4; ++b) { gacc[a][b][0] = 0.f; gacc[a][b][1] = 0.f; }
  }

  f32x4 acc[4][4];
  int e = 0; float gate = 1.f; int lp = bx;
  float bv[4];

  for (int kp = 0; kp < NK; ++kp) {
    if (OMODE == 1) {
      const int gp = (pair0 + bx) * 3 + kp;  // pair0 = batch offset
      e = pe[gp]; gate = pg[gp]; lp = bx * 3 + kp;
    } else if (OMODE == 2) { lp = bx; e = 0; }
    else { lp = bx; e = pe[pair0 + bx]; }

#pragma unroll
    for (int a = 0; a < 4; ++a)
#pragma unroll
      for (int b = 0; b < 4; ++b) acc[a][b] = (f32x4){0.f, 0.f, 0.f, 0.f};

    const size_t xbase = ((size_t)lp * (L + 2) + lz) * CI;

    for (int kc = 0; kc < KC; ++kc) {
      const int c0 = kc * 32;
#pragma unroll
      for (int it = 0; it < XIT; ++it) {
        const int g = it * 256 + t;
        if (g < XG) {
          const int pl = g >= XG / 2;
          const int r = g - pl * (XG / 2);
          const int row = r >> 2;
          const int c16 = r & 3;
          const ushort* src =
              (pl ? xl : xh) + xbase + (size_t)row * CI + c0 + c16 * 8;
          gload_lds16(src, xsf + (size_t)g * 8);
        }
      }
#pragma unroll
      for (int it = 0; it < WIT; ++it) {
        const int g = it * 256 + t;
        const int pl = g >= WG / 2;
        const int r = g - pl * (WG / 2);
        const int tp = r / (CT * 4);
        const int rr = r % (CT * 4);
        const int co = rr >> 2;
        const int c16 = rr & 3;
        const ushort* src = (pl ? wl : wh) +
            ((((size_t)e * 3 + tp) * KC + kc) * CO + cb + co) * 32 + c16 * 8;
        gload_lds16(src, wsf + (size_t)g * 8);
      }
      __syncthreads();  // compiler drains vmcnt before s_barrier

      __builtin_amdgcn_s_setprio(1);
#pragma unroll
      for (int tp = 0; tp < 3; ++tp) {
        s8v a0[4], a1[4];
#pragma unroll
        for (int lt = 0; lt < 4; ++lt) {
          const int row = wvl * 64 + lt * 16 + l16 + tp;
          a0[lt] = *reinterpret_cast<const s8v*>(&xs[0][row][kb8]);
          a1[lt] = *reinterpret_cast<const s8v*>(&xs[1][row][kb8]);
        }
#pragma unroll
        for (int cs = 0; cs < 4; ++cs) {
          const int brow = wvc * 64 + cs * 16 + l16;
          s8v bh = *reinterpret_cast<const s8v*>(&wsm[0][tp][brow][kb8]);
          s8v bl = *reinterpret_cast<const s8v*>(&wsm[1][tp][brow][kb8]);
#pragma unroll
          for (int lt = 0; lt < 4; ++lt) {
            acc[lt][cs] = __builtin_amdgcn_mfma_f32_16x16x32_bf16(a0[lt], bh, acc[lt][cs], 0, 0, 0);
            acc[lt][cs] = __builtin_amdgcn_mfma_f32_16x16x32_bf16(a0[lt], bl, acc[lt][cs], 0, 0, 0);
            acc[lt][cs] = __builtin_amdgcn_mfma_f32_16x16x32_bf16(a1[lt], bh, acc[lt][cs], 0, 0, 0);
          }
        }
      }
      __builtin_amdgcn_s_setprio(0);
      __syncthreads();
    }

#pragma unroll
    for (int cs = 0; cs < 4; ++cs)
      bv[cs] = bias[(size_t)e * CO + cb + wvc * 64 + cs * 16 + l16];

    if (OMODE == 1) {
#pragma unroll
      for (int lt = 0; lt < 4; ++lt)
#pragma unroll
        for (int cs = 0; cs < 4; ++cs)
#pragma unroll
          for (int q = 0; q < 2; ++q) {
            const float v0 = acc[lt][cs][q * 2] + bv[cs];
            const float v1 = acc[lt][cs][q * 2 + 1] + bv[cs];
            const float m = fmaxf(fmaxf(v0, v1), 0.f);
            gacc[lt][cs][q] += gate * m;
          }
    }
  }

  if (OMODE == 0) {
#pragma unroll
    for (int lt = 0; lt < 4; ++lt)
#pragma unroll
      for (int cs = 0; cs < 4; ++cs)
#pragma unroll
        for (int r = 0; r < 4; ++r) {
          const int l = lz + wvl * 64 + lt * 16 + (lane >> 4) * 4 + r;
          const float v = acc[lt][cs][r] + bv[cs];
          const size_t o =
              ((size_t)lp * (L + 2) + 1 + l) * CO + cb + wvc * 64 + cs * 16 + l16;
          const ushort hi = f2bf(v);
          oh[o] = hi;
          ol[o] = f2bf(v - bf2f(hi));
        }
    if (blockIdx.z == 0 && t < CT) {
      const size_t o0 = (size_t)lp * (L + 2) * CO + cb + t;
      const size_t o1 = ((size_t)lp * (L + 2) + (L + 1)) * CO + cb + t;
      oh[o0] = 0; ol[o0] = 0; oh[o1] = 0; ol[o1] = 0;
    }
  } else if (OMODE == 3) {
#pragma unroll
    for (int lt = 0; lt < 4; ++lt)
#pragma unroll
      for (int cs = 0; cs < 4; ++cs)
#pragma unroll
        for (int r = 0; r < 4; r += 2) {
          const float v0 = acc[lt][cs][r] + bv[cs];
          const float v1 = acc[lt][cs][r + 1] + bv[cs];
          const float m = fmaxf(fmaxf(v0, v1), 0.f);
          const int lpp = (lz + wvl * 64 + lt * 16 + (lane >> 4) * 4 + r) >> 1;
          const size_t o = ((size_t)lp * (L / 2 + 2) + 1 + lpp) * CO + cb +
                           wvc * 64 + cs * 16 + l16;
          const ushort hi = f2bf(m);
          oh[o] = hi;
          ol[o] = f2bf(m - bf2f(hi));
        }
    if (blockIdx.z == 0 && t < CT) {
      const size_t o0 = (size_t)lp * (L / 2 + 2) * CO + cb + t;
      const size_t o1 = ((size_t)lp * (L / 2 + 2) + (L / 2 + 1)) * CO + cb + t;
      oh[o0] = 0; ol[o0] = 0; oh[o1] = 0; ol[o1] = 0;
    }
  } else if (OMODE == 1) {
    // gated sum -> bf16 hi/lo in [B][L/2+2][CO] halo layout
#pragma unroll
    for (int lt = 0; lt < 4; ++lt)
#pragma unroll
      for (int cs = 0; cs < 4; ++cs)
#pragma unroll
        for (int q = 0; q < 2; ++q) {
          const int lpp =
              (lz + wvl * 64 + lt * 16 + (lane >> 4) * 4 + q * 2) >> 1;
          const int co = cb + wvc * 64 + cs * 16 + l16;
          const size_t o =
              ((size_t)(pair0 + bx) * (L / 2 + 2) + 1 + lpp) * CO + co;
          const float g = gacc[lt][cs][q];
          const ushort hi = f2bf(g);
          oh[o] = hi;
          ol[o] = f2bf(g - bf2f(hi));
        }
    if (blockIdx.z == 0 && t < CT) {
      const size_t o0 = (size_t)(pair0 + bx) * (L / 2 + 2) * CO + cb + t;
      const size_t o1 =
          ((size_t)(pair0 + bx) * (L / 2 + 2) + (L / 2 + 1)) * CO + cb + t;
      oh[o0] = 0; ol[o0] = 0; oh[o1] = 0; ol[o1] = 0;
    }
  } else {
#pragma unroll
    for (int lt = 0; lt < 4; ++lt)
#pragma unroll
      for (int cs = 0; cs < 4; ++cs)
#pragma unroll
        for (int r = 0; r < 4; r += 2) {
          const float v0 = acc[lt][cs][r] + bv[cs];
          const float v1 = acc[lt][cs][r + 1] + bv[cs];
          const float m = fmaxf(fmaxf(v0, v1), 0.f);
          const int lpp = (lz + wvl * 64 + lt * 16 + (lane >> 4) * 4 + r) >> 1;
          const int co = cb + wvc * 64 + cs * 16 + l16;
          const size_t o = ((size_t)lp * CO + co) * (L / 2) + lpp;
          of[o] = m;
        }
  }
}

// ---------------------------------------------------------------------------
// fc1 MFMA split-bf16 GEMM
// ---------------------------------------------------------------------------
__global__ __launch_bounds__(256) void fc1M_k(const float* __restrict__ X,
                                              const float* __restrict__ W,
                                              float* __restrict__ part)
{
  __shared__ ushort xs[2][128][32];
  __shared__ ushort wsm[2][64][32];
  const int t = threadIdx.x;
  const int lane = t & 63;
  const int wv = t >> 6;
  const int l16 = lane & 15;
  const int kb8 = (lane >> 4) * 8;
  const int ot = blockIdx.x * 64;
  const size_t k0g = (size_t)blockIdx.y * 512;

  f32x4 acc[2][4];
#pragma unroll
  for (int a = 0; a < 2; ++a)
#pragma unroll
    for (int b = 0; b < 4; ++b) acc[a][b] = (f32x4){0.f, 0.f, 0.f, 0.f};

  const int xrow = t >> 1;
  const int xcol = (t & 1) * 16;
  const int wco  = t >> 2;
  const int wk   = (t & 3) * 8;

  for (int it = 0; it < 16; ++it) {
    const size_t k0 = k0g + it * 32;
    {
      const float* src = X + (size_t)xrow * 65536 + k0 + xcol;
      float v[16];
#pragma unroll
      for (int q = 0; q < 4; ++q)
        *reinterpret_cast<float4*>(&v[q * 4]) =
            *reinterpret_cast<const float4*>(src + q * 4);
#pragma unroll
      for (int q = 0; q < 2; ++q) {
        u16x8 hv, lv;
#pragma unroll
        for (int j = 0; j < 8; ++j) {
          const float f = v[q * 8 + j];
          const ushort h = f2bf(f);
          hv[j] = h;
          lv[j] = f2bf(f - bf2f(h));
        }
        *reinterpret_cast<u16x8*>(&xs[0][xrow][xcol + q * 8]) = hv;
        *reinterpret_cast<u16x8*>(&xs[1][xrow][xcol + q * 8]) = lv;
      }
    }
    {
      const float* src = W + (size_t)(ot + wco) * 65536 + k0 + wk;
      float v[8];
      *reinterpret_cast<float4*>(&v[0]) = *reinterpret_cast<const float4*>(src);
      *reinterpret_cast<float4*>(&v[4]) = *reinterpret_cast<const float4*>(src + 4);
      u16x8 hv, lv;
#pragma unroll
      for (int j = 0; j < 8; ++j) {
        const ushort h = f2bf(v[j]);
        hv[j] = h;
        lv[j] = f2bf(v[j] - bf2f(h));
      }
      *reinterpret_cast<u16x8*>(&wsm[0][wco][wk]) = hv;
      *reinterpret_cast<u16x8*>(&wsm[1][wco][wk]) = lv;
    }
    __syncthreads();
    __builtin_amdgcn_s_setprio(1);
#pragma unroll
    for (int ms = 0; ms < 2; ++ms) {
      const int ar = wv * 32 + ms * 16 + l16;
      s8v ah = *reinterpret_cast<const s8v*>(&xs[0][ar][kb8]);
      s8v al = *reinterpret_cast<const s8v*>(&xs[1][ar][kb8]);
#pragma unroll
      for (int cs = 0; cs < 4; ++cs) {
        const int brow = cs * 16 + l16;
        s8v bh = *reinterpret_cast<const s8v*>(&wsm[0][brow][kb8]);
        s8v bl = *reinterpret_cast<const s8v*>(&wsm[1][brow][kb8]);
        acc[ms][cs] = __builtin_amdgcn_mfma_f32_16x16x32_bf16(ah, bh, acc[ms][cs], 0, 0, 0);
        acc[ms][cs] = __builtin_amdgcn_mfma_f32_16x16x32_bf16(ah, bl, acc[ms][cs], 0, 0, 0);
        acc[ms][cs] = __builtin_amdgcn_mfma_f32_16x16x32_bf16(al, bh, acc[ms][cs], 0, 0, 0);
      }
    }
    __builtin_amdgcn_s_setprio(0);
    __syncthreads();
  }

#pragma unroll
  for (int ms = 0; ms < 2; ++ms)
#pragma unroll
    for (int cs = 0; cs < 4; ++cs)
#pragma unroll
      for (int r = 0; r < 4; ++r) {
        const int row = wv * 32 + ms * 16 + (lane >> 4) * 4 + r;
        const int col = ot + cs * 16 + l16;
        part[((size_t)blockIdx.y * 128 + row) * 256 + col] = acc[ms][cs][r];
      }
}

__global__ void fc1red_k(const float* __restrict__ part,
                         const float* __restrict__ b1, float* __restrict__ o1)
{
  const int idx = blockIdx.x * 256 + threadIdx.x;
  if (idx < 32768) {
    float s = 0.f;
#pragma unroll 8
    for (int z = 0; z < 128; ++z) s += part[(size_t)z * 32768 + idx];
    o1[idx] = fmaxf(s + b1[idx & 255], 0.f);
  }
}

__global__ void fc2_k(const float* __restrict__ o1, const float* __restrict__ w2,
                      const float* __restrict__ b2, float* __restrict__ out)
{
  const int b = blockIdx.x;
  const int lane = threadIdx.x;
  float acc[5] = {0.f, 0.f, 0.f, 0.f, 0.f};
  for (int i = lane; i < 256; i += 64) {
    const float xv = o1[(size_t)b * 256 + i];
#pragma unroll
    for (int o = 0; o < 5; ++o) acc[o] = fmaf(xv, w2[o * 256 + i], acc[o]);
  }
#pragma unroll
  for (int o = 0; o < 5; ++o) {
    for (int off = 32; off > 0; off >>= 1)
      acc[o] += __shfl_down(acc[o], off, 64);
  }
  if (lane == 0) {
#pragma unroll
    for (int o = 0; o < 5; ++o) out[b * 5 + o] = acc[o] + b2[o];
  }
}

// ---------------------------------------------------------------------------
// launcher
// ---------------------------------------------------------------------------
extern "C" void kernel_launch(void* const* d_in, const int* in_sizes, int n_in,
                              void* d_out, int out_size, void* d_ws,
                              size_t ws_size, hipStream_t stream)
{
  const float* x   = (const float*)d_in[0];
  const float* c1w = (const float*)d_in[1];
  const float* c1b = (const float*)d_in[2];
  const float* ew[6];
  const float* eb[6];
  for (int j = 0; j < 6; ++j) {
    ew[j] = (const float*)d_in[3 + 2 * j];
    eb[j] = (const float*)d_in[4 + 2 * j];
  }
  const float* rw  = (const float*)d_in[15];
  const float* rb  = (const float*)d_in[16];
  const float* c2w = (const float*)d_in[17];
  const float* c2b = (const float*)d_in[18];
  const float* f1w = (const float*)d_in[19];
  const float* f1b = (const float*)d_in[20];
  const float* f2w = (const float*)d_in[21];
  const float* f2b = (const float*)d_in[22];
  float* out = (float*)d_out;

  const int chunkB = 32;
  const int chunkP = chunkB * 3;          // 96
  const int nchunk = 128 / chunkB;        // 4

  char* basep = (char*)d_ws;
  size_t off = 0;
  auto alloc = [&](size_t bytes) -> void* {
    off = (off + 255) & ~(size_t)255;
    void* r = basep + off;
    off += bytes;
    return r;
  };

  float* h      = (float*)alloc(2097152ull * 4);
  float* pooled = (float*)alloc(2048ull * 4);
  float* pairg  = (float*)alloc(384ull * 4);
  int*   paire  = (int*)  alloc(384ull * 4);
  float* fc1o   = (float*)alloc(32768ull * 4);

  // xtF: [128][130][512] hi/lo bf16 = 34.1 MB (part 16.8 MB aliases later)
  ushort* xtFh  = (ushort*)alloc(8519680ull * 2 * 2);
  ushort* xtFl  = xtFh + 8519680ull;
  float*  part  = (float*)xtFh;

  // chunk ping-pong slots; comb (33.5 MB) aliases slotA+slotB (38.0 MB)
  const size_t slot_base = (off + 255) & ~(size_t)255;
  char* slotA = (char*)alloc((size_t)chunkP * 33024 * 2 * 2);  // 12.7 MB
  char* slotB = (char*)alloc((size_t)chunkP * 66048 * 2 * 2);  // 25.4 MB
  float* comb = (float*)(basep + slot_base);

  float*  bufA  = (float*)slotA;
  ushort* xt3h  = (ushort*)slotA;
  ushort* xt3l  = xt3h + (size_t)chunkP * 16448;
  ushort* xt5h  = (ushort*)slotA;
  ushort* xt5l  = xt5h + (size_t)chunkP * 33024;
  float*  bufB  = (float*)slotB;
  ushort* yE3h  = (ushort*)slotB;
  ushort* yE3l  = yE3h + (size_t)chunkP * 32896;
  ushort* y5h   = (ushort*)slotB;
  ushort* y5l   = y5h + (size_t)chunkP * 66048;

  ushort* wp3h  = (ushort*)alloc(49152ull * 2);
  ushort* wp3l  = (ushort*)alloc(49152ull * 2);
  ushort* wp4h  = (ushort*)alloc(196608ull * 2);
  ushort* wp4l  = (ushort*)alloc(196608ull * 2);
  ushort* wp5h  = (ushort*)alloc(786432ull * 2);
  ushort* wp5l  = (ushort*)alloc(786432ull * 2);
  ushort* wp6h  = (ushort*)alloc(3145728ull * 2);
  ushort* wp6l  = (ushort*)alloc(3145728ull * 2);
  ushort* wpFh  = (ushort*)alloc(1572864ull * 2);
  ushort* wpFl  = (ushort*)alloc(1572864ull * 2);

  conv1_k<<<128, 256, 0, stream>>>(x, c1w, c1b, h, pooled);
  router_k<<<1, 128, 0, stream>>>(pooled, rw, rb, pairg, paire, out + 640);

  wprep_k<<<(49152 + 255) / 256, 256, 0, stream>>>(ew[2], wp3h, wp3l, 8, 64, 32, 49152);
  wprep_k<<<(196608 + 255) / 256, 256, 0, stream>>>(ew[3], wp4h, wp4l, 8, 128, 64, 196608);
  wprep_k<<<(786432 + 255) / 256, 256, 0, stream>>>(ew[4], wp5h, wp5l, 8, 256, 128, 786432);
  wprep_k<<<(3145728 + 255) / 256, 256, 0, stream>>>(ew[5], wp6h, wp6l, 8, 512, 256, 3145728);
  wprep_k<<<(1572864 + 255) / 256, 256, 0, stream>>>(c2w, wpFh, wpFl, 1, 1024, 512, 1572864);

  for (int c = 0; c < nchunk; ++c) {
    const int b0 = c * chunkB;
    const int p0 = c * chunkP;
    convR_k<16, 16, 1024, false, 16, 16, 4, 3>
        <<<dim3(chunkP, 1, 4), 256, 0, stream>>>(
            h + (size_t)b0 * 16 * 1024, ew[0], eb[0], bufA, paire + p0);
    convR_k<16, 32, 1024, true, 16, 32, 8, 1>
        <<<dim3(chunkP, 1, 4), 256, 0, stream>>>(bufA, ew[1], eb[1], bufB,
                                                 paire + p0);
    t0_k<<<dim3(chunkP, 16), 256, 0, stream>>>(bufB, xt3h, xt3l);
    convM_k<32, 64, 512, 0>
        <<<dim3(chunkP, 1, 4), 256, 0, stream>>>(xt3h, xt3l, wp3h, wp3l, eb[2],
                                                 yE3h, yE3l, nullptr, paire,
                                                 nullptr, p0);
    convM2_k<64, 128, 512, 3, 4, 1>
        <<<dim3(chunkP, 2, 2), 256, 0, stream>>>(yE3h, yE3l, wp4h, wp4l, eb[3],
                                                 xt5h, xt5l, nullptr, paire,
                                                 nullptr, p0);
    convM2_k<128, 256, 256, 0, 4, 1>
        <<<dim3(chunkP, 4, 1), 256, 0, stream>>>(xt5h, xt5l, wp5h, wp5l, eb[4],
                                                 y5h, y5l, nullptr, paire,
                                                 nullptr, p0);
    // e6: 3 top-k pairs looped in-kernel, gated sum -> xtF bf16 (t2 fused)
    convM2_k<256, 512, 256, 1, 4, 1>
        <<<dim3(chunkB, 8, 1), 256, 0, stream>>>(y5h, y5l, wp6h, wp6l, eb[5],
                                                 xtFh, xtFl, nullptr,
                                                 paire, pairg, b0);
  }

  convM2_k<512, 1024, 128, 2, 2, 2>
      <<<dim3(128, 8, 1), 256, 0, stream>>>(xtFh, xtFl, wpFh, wpFl, c2b,
                                            nullptr, nullptr, comb, nullptr,
                                            nullptr, 0);

  fc1M_k<<<dim3(4, 128), 256, 0, stream>>>(comb, f1w, part);
  fc1red_k<<<128, 256, 0, stream>>>(part, f1b, fc1o);
  fc2_k<<<128, 64, 0, stream>>>(fc1o, f2w, f2b, out);
}

// Round 14
// 643.176 us; speedup vs baseline: 1.1664x; 1.1664x over previous
//
#include <hip/hip_runtime.h>
#include <hip/hip_bf16.h>
#include <math.h>

#define B_   128
#define L_   1024
#define E_   8
#define K_   3

typedef float f32x4 __attribute__((ext_vector_type(4)));
typedef short s8v  __attribute__((ext_vector_type(8)));
typedef unsigned short u16x8 __attribute__((ext_vector_type(8)));

__device__ inline ushort f2bf(float v) {
  union { float f; unsigned u; } x; x.f = v;
  unsigned r = (x.u + 0x7fffu + ((x.u >> 16) & 1u)) >> 16;
  return (ushort)r;
}
__device__ inline float bf2f(ushort h) {
  union { unsigned u; float f; } x; x.u = ((unsigned)h) << 16;
  return x.f;
}

// async global->LDS DMA, 16B/lane; dest linear in granule index.
__device__ __forceinline__ void gload_lds16(const ushort* g, ushort* l) {
  __builtin_amdgcn_global_load_lds(
      (const __attribute__((address_space(1))) unsigned int*)g,
      (__attribute__((address_space(3))) unsigned int*)l, 16, 0, 0);
}

// ---------------------------------------------------------------------------
// conv1: x[128,1,1024] -> h[128,16,1024] (ReLU) + pooled[128,16]
// ---------------------------------------------------------------------------
__global__ __launch_bounds__(256) void conv1_k(
    const float* __restrict__ x, const float* __restrict__ w,
    const float* __restrict__ bias, float* __restrict__ h,
    float* __restrict__ pooled)
{
  const int b = blockIdx.x;
  const int t = threadIdx.x;
  __shared__ float xs[1026];
  __shared__ float wsm[48];
  __shared__ float bs[16];
  __shared__ float red[4][16];

  for (int i = t; i < 1024; i += 256) xs[i + 1] = x[(size_t)b * 1024 + i];
  if (t == 0) { xs[0] = 0.f; xs[1025] = 0.f; }
  if (t < 48) wsm[t] = w[t];
  if (t < 16) bs[t] = bias[t];
  __syncthreads();

  float ps[16];
#pragma unroll
  for (int c = 0; c < 16; ++c) ps[c] = 0.f;

  for (int li = 0; li < 4; ++li) {
    const int l = t + li * 256;
    const float xm = xs[l], x0 = xs[l + 1], xp = xs[l + 2];
#pragma unroll
    for (int co = 0; co < 16; ++co) {
      float v = fmaf(wsm[co * 3 + 0], xm,
                fmaf(wsm[co * 3 + 1], x0,
                fmaf(wsm[co * 3 + 2], xp, bs[co])));
      v = fmaxf(v, 0.f);
      h[((size_t)b * 16 + co) * 1024 + l] = v;
      ps[co] += v;
    }
  }
#pragma unroll
  for (int co = 0; co < 16; ++co) {
    float v = ps[co];
    for (int off = 32; off > 0; off >>= 1) v += __shfl_down(v, off, 64);
    ps[co] = v;
  }
  const int wid = t >> 6, lane = t & 63;
  if (lane == 0) {
#pragma unroll
    for (int co = 0; co < 16; ++co) red[wid][co] = ps[co];
  }
  __syncthreads();
  if (t < 16) pooled[(size_t)b * 16 + t] =
      (red[0][t] + red[1][t] + red[2][t] + red[3][t]) * (1.f / 1024.f);
}

// ---------------------------------------------------------------------------
// router: pooled -> top3 gates + cv^2
// ---------------------------------------------------------------------------
__global__ void router_k(const float* __restrict__ pooled,
                         const float* __restrict__ rw,
                         const float* __restrict__ rb,
                         float* __restrict__ pair_g, int* __restrict__ pair_e,
                         float* __restrict__ cv2_out)
{
  const int b = threadIdx.x;  // 0..127
  __shared__ float pl[128][8];
  __shared__ float mp[8];

  float pv[16];
#pragma unroll
  for (int i = 0; i < 16; ++i) pv[i] = pooled[(size_t)b * 16 + i];

  float lg[8];
#pragma unroll
  for (int e = 0; e < 8; ++e) {
    float s = rb[e];
#pragma unroll
    for (int i = 0; i < 16; ++i) s = fmaf(pv[i], rw[e * 16 + i], s);
    lg[e] = s;
  }
  float mx = lg[0];
#pragma unroll
  for (int e = 1; e < 8; ++e) mx = fmaxf(mx, lg[e]);
  float pr[8]; float sum = 0.f;
#pragma unroll
  for (int e = 0; e < 8; ++e) { pr[e] = expf(lg[e] - mx); sum += pr[e]; }
  const float inv = 1.f / sum;
#pragma unroll
  for (int e = 0; e < 8; ++e) { pr[e] *= inv; pl[b][e] = pr[e]; }

  bool used[8] = {false,false,false,false,false,false,false,false};
  float tg[3]; int ti[3];
  for (int k = 0; k < 3; ++k) {
    float best = -1.f; int bi = 0;
#pragma unroll
    for (int e = 0; e < 8; ++e)
      if (!used[e] && pr[e] > best) { best = pr[e]; bi = e; }
    used[bi] = true; tg[k] = best; ti[k] = bi;
  }
  const float ts = 1.f / (tg[0] + tg[1] + tg[2]);
  for (int k = 0; k < 3; ++k) {
    pair_g[b * 3 + k] = tg[k] * ts;
    pair_e[b * 3 + k] = ti[k];
  }
  __syncthreads();
  if (b < 8) {
    float s = 0.f;
    for (int i = 0; i < 128; ++i) s += pl[i][b];
    mp[b] = s * (1.f / 128.f);
  }
  __syncthreads();
  if (b == 0) {
    float m = 0.f;
    for (int e = 0; e < 8; ++e) m += mp[e];
    m *= (1.f / 8.f);
    float v = 0.f;
    for (int e = 0; e < 8; ++e) { float d = mp[e] - m; v += d * d; }
    v *= (1.f / 7.f);
    const float cv = sqrtf(v) / (m + 1e-10f);
    cv2_out[0] = cv * cv;
  }
}

// ---------------------------------------------------------------------------
// Vector conv (e1, e2 only)
// ---------------------------------------------------------------------------
template <int CI, int CO, int LIN, bool POOL, int CIC, int CO_T, int CO_R,
          int IN_DIV>
__global__ __launch_bounds__(256) void convR_k(
    const float* __restrict__ in, const float* __restrict__ w,
    const float* __restrict__ bias, float* __restrict__ out,
    const int* __restrict__ pe)
{
  constexpr int CQ  = CO_T / CO_R;
  constexpr int LQ  = 256 / CQ;
  constexpr int L_T = LQ * 4;
  constexpr int LOUT = POOL ? (LIN / 2) : LIN;
  constexpr int RS  = L_T + 8;
  constexpr int CG  = CO_R / 4;

  const int p  = blockIdx.x;
  const int cb = blockIdx.y * CO_T;
  const int l0 = blockIdx.z * L_T;
  const int e  = pe ? pe[p] : 0;
  const float* inp = in + (size_t)(p / IN_DIV) * CI * LIN;
  const float* wp  = w + (size_t)e * CO * CI * 3;

  __shared__ float in_s[CIC * RS];
  __shared__ float w_s[CIC * 3 * CO_T];

  const int t  = threadIdx.x;
  const int cq = t / LQ;
  const int lq = t % LQ;

  float acc[CO_R][4];
#pragma unroll
  for (int c = 0; c < CO_R; ++c)
#pragma unroll
    for (int l = 0; l < 4; ++l) acc[c][l] = 0.f;

  for (int c0 = 0; c0 < CI; c0 += CIC) {
    for (int idx = t; idx < CIC * (L_T + 2); idx += 256) {
      const int ci = idx / (L_T + 2);
      const int j  = idx - ci * (L_T + 2);
      const int gl = l0 + j - 1;
      in_s[ci * RS + j] =
          (gl >= 0 && gl < LIN) ? inp[(size_t)(c0 + ci) * LIN + gl] : 0.f;
    }
    for (int i = t; i < CIC * CO_T; i += 256) {
      const int co = i % CO_T;
      const int ci = i / CO_T;
      const float* wsrc = wp + ((size_t)(cb + co) * CI + (c0 + ci)) * 3;
      const float w0 = wsrc[0], w1 = wsrc[1], w2 = wsrc[2];
      w_s[(ci * 3 + 0) * CO_T + co] = w0;
      w_s[(ci * 3 + 1) * CO_T + co] = w1;
      w_s[(ci * 3 + 2) * CO_T + co] = w2;
    }
    __syncthreads();
#pragma unroll 4
    for (int ci = 0; ci < CIC; ++ci) {
      const float* row = &in_s[ci * RS + lq * 4];
      const float4 xa = *reinterpret_cast<const float4*>(row);
      const float2 xb = *reinterpret_cast<const float2*>(row + 4);
      const float xv[6] = {xa.x, xa.y, xa.z, xa.w, xb.x, xb.y};
      const float* wrow = &w_s[ci * 3 * CO_T + cq * CO_R];
#pragma unroll
      for (int k = 0; k < 3; ++k) {
#pragma unroll
        for (int cg = 0; cg < CG; ++cg) {
          const float4 wv =
              *reinterpret_cast<const float4*>(&wrow[k * CO_T + cg * 4]);
          const float wq[4] = {wv.x, wv.y, wv.z, wv.w};
#pragma unroll
          for (int c = 0; c < 4; ++c)
#pragma unroll
            for (int l = 0; l < 4; ++l)
              acc[cg * 4 + c][l] = fmaf(wq[c], xv[l + k], acc[cg * 4 + c][l]);
        }
      }
    }
    __syncthreads();
  }

#pragma unroll
  for (int c = 0; c < CO_R; ++c) {
    const int co = cb + cq * CO_R + c;
    const float bv = bias[(size_t)e * CO + co];
    const float v0 = acc[c][0] + bv, v1 = acc[c][1] + bv;
    const float v2 = acc[c][2] + bv, v3 = acc[c][3] + bv;
    float* op = out + ((size_t)p * CO + co) * LOUT;
    if (POOL) {
      const int lo = (l0 >> 1) + lq * 2;
      float2 r;
      r.x = fmaxf(fmaxf(v0, v1), 0.f);
      r.y = fmaxf(fmaxf(v2, v3), 0.f);
      *reinterpret_cast<float2*>(&op[lo]) = r;
    } else {
      const int l = l0 + lq * 4;
      *reinterpret_cast<float4*>(&op[l]) = make_float4(v0, v1, v2, v3);
    }
  }
}

// ---------------------------------------------------------------------------
// Merged weight prep: 5 segments, fp32 [E][CO][CI][3] -> hi/lo bf16
// [E][3][CI/32][CO][32]. One launch instead of 5.
// ---------------------------------------------------------------------------
struct WSeg { const float* w; ushort* oh; ushort* ol; int CO; int CI; int n; };

__global__ void wprepAll_k(const float* w3, const float* w4,
                           const float* w5, const float* w6,
                           const float* wF,
                           ushort* o3h, ushort* o3l, ushort* o4h, ushort* o4l,
                           ushort* o5h, ushort* o5l, ushort* o6h, ushort* o6l,
                           ushort* oFh, ushort* oFl)
{
  int idx = blockIdx.x * 256 + threadIdx.x;
  const float* w; ushort* oh; ushort* ol; int CO, CI;
  if (idx < 49152)        { w = w3; oh = o3h; ol = o3l; CO = 64;   CI = 32;  }
  else if (idx < 245760)  { idx -= 49152;
                            w = w4; oh = o4h; ol = o4l; CO = 128;  CI = 64;  }
  else if (idx < 1032192) { idx -= 245760;
                            w = w5; oh = o5h; ol = o5l; CO = 256;  CI = 128; }
  else if (idx < 4177920) { idx -= 1032192;
                            w = w6; oh = o6h; ol = o6l; CO = 512;  CI = 256; }
  else if (idx < 5750784) { idx -= 4177920;
                            w = wF; oh = oFh; ol = oFl; CO = 1024; CI = 512; }
  else return;

  const int KC = CI >> 5;
  const int j = idx & 31;
  int r = idx >> 5;
  const int co = r % CO; r /= CO;
  const int kc = r % KC; r /= KC;
  const int tp = r % 3;
  const int e  = r / 3;
  const float v = w[(((size_t)e * CO + co) * CI + (kc * 32 + j)) * 3 + tp];
  const ushort hi = f2bf(v);
  oh[idx] = hi;
  ol[idx] = f2bf(v - bf2f(hi));
}

// ---------------------------------------------------------------------------
// t0: e2 out fp32 [P][32][512] -> xt3 hi/lo bf16 [P][514][32] (halo rows 0)
// ---------------------------------------------------------------------------
__global__ __launch_bounds__(256) void t0_k(const float* __restrict__ in,
                                            ushort* __restrict__ oh,
                                            ushort* __restrict__ ol)
{
  __shared__ float tile[32][33];
  const int p  = blockIdx.x;
  const int l0 = blockIdx.y * 32;
  const int tx = threadIdx.x & 31;
  const int ty = threadIdx.x >> 5;

#pragma unroll
  for (int i = 0; i < 4; ++i) {
    const int ci = ty + i * 8;
    tile[ci][tx] = in[(size_t)p * 16384 + (size_t)ci * 512 + l0 + tx];
  }
  __syncthreads();
#pragma unroll
  for (int i = 0; i < 4; ++i) {
    const int l = l0 + ty + i * 8;
    const float v = tile[tx][ty + i * 8];
    const size_t o = ((size_t)p * 514 + 1 + l) * 32 + tx;
    const ushort hi = f2bf(v);
    oh[o] = hi;
    ol[o] = f2bf(v - bf2f(hi));
  }
  if (blockIdx.y == 0 && threadIdx.x < 32) {
    const size_t o0 = (size_t)p * 514 * 32 + threadIdx.x;
    const size_t o1 = ((size_t)p * 514 + 513) * 32 + threadIdx.x;
    oh[o0] = 0; ol[o0] = 0; oh[o1] = 0; ol[o1] = 0;
  }
}

// ---------------------------------------------------------------------------
// MFMA conv1d (k=3, pad=1), split-bf16 (hi/lo), 16x16x32 bf16 MFMA.
// X: [NP][L+2][CI] hi/lo bf16, W: [E][3][CI/32][CO][32]; BOTH staged to LDS
// via global_load_lds. Block: 256 thr = 4 waves stacked in l. Block tile:
// 128 l x 64 co. 41.2KB LDS -> 3 blocks/CU (proven optimum of this 2-barrier
// schedule; larger tiles at 2 blocks/CU regressed twice).
// D: col=lane&15, row=(lane>>4)*4+reg (HW-verified layout).
// OMODE 0: plain conv -> bf16 hi/lo out [NP][L+2][CO] (halo zeroed)
// OMODE 1: relu+pool; loops the 3 top-k pairs of batch (pair0+bx) INTERNALLY,
//          gacc += gate*relu(pool(conv)); writes bf16 hi/lo DIRECTLY in the
//          next conv's [B][L/2+2][CO] halo layout (t2 fused away)
// OMODE 2: relu+pool, fp32 transposed [NP][CO][L/2]
// OMODE 3: relu+pool -> bf16 hi/lo out [NP][L/2+2][CO] (halo zeroed)
// ---------------------------------------------------------------------------
template <int CI, int CO, int L, int OMODE>
__global__ __launch_bounds__(256) void convM_k(
    const ushort* __restrict__ xh, const ushort* __restrict__ xl,
    const ushort* __restrict__ wh, const ushort* __restrict__ wl,
    const float* __restrict__ bias,
    ushort* __restrict__ oh, ushort* __restrict__ ol,
    float* __restrict__ of,
    const int* __restrict__ pe, const float* __restrict__ pg,
    int pair0)
{
  constexpr int KC = CI / 32;
  constexpr int NK = (OMODE == 1) ? 3 : 1;
  const int bx = blockIdx.x;
  const int cb = blockIdx.y * 64;
  const int lz = blockIdx.z * 128;

  __shared__ ushort xs[2][130][32];
  __shared__ ushort wsm[2][3][64][32];
  ushort* xsf = &xs[0][0][0];
  ushort* wsf = &wsm[0][0][0][0];

  const int t = threadIdx.x;
  const int lane = t & 63;
  const int wv = t >> 6;
  const int l16 = lane & 15;
  const int kb8 = (lane >> 4) * 8;

  float gacc[2][4][2];
  if (OMODE == 1) {
#pragma unroll
    for (int a = 0; a < 2; ++a)
#pragma unroll
      for (int b = 0; b < 4; ++b) { gacc[a][b][0] = 0.f; gacc[a][b][1] = 0.f; }
  }

  f32x4 acc[2][4];
  int e = 0; float gate = 1.f; int lp = bx;
  float bv[4];

  for (int kp = 0; kp < NK; ++kp) {
    if (OMODE == 1) {
      const int gp = (pair0 + bx) * 3 + kp;  // pair0 = batch offset here
      e = pe[gp]; gate = pg[gp]; lp = bx * 3 + kp;
    } else if (OMODE == 2) { lp = bx; e = 0; }
    else { lp = bx; e = pe[pair0 + bx]; }

#pragma unroll
    for (int a = 0; a < 2; ++a)
#pragma unroll
      for (int b = 0; b < 4; ++b) acc[a][b] = (f32x4){0.f, 0.f, 0.f, 0.f};

    const size_t xbase = ((size_t)lp * (L + 2) + lz) * CI;

    for (int kc = 0; kc < KC; ++kc) {
      const int c0 = kc * 32;
      // X: 1040 granules (2 planes x 130 rows x 4), dest linear = xsf + g*8
#pragma unroll
      for (int it = 0; it < 5; ++it) {
        const int g = it * 256 + t;
        if (g < 1040) {
          const int pl = g >= 520;
          const int r = g - pl * 520;
          const int row = r >> 2;
          const int c16 = r & 3;
          const ushort* src =
              (pl ? xl : xh) + xbase + (size_t)row * CI + c0 + c16 * 8;
          gload_lds16(src, xsf + (size_t)g * 8);
        }
      }
      // W: 1536 granules (2 planes x 3 taps x 64 co x 4), dest = wsf + g*8
#pragma unroll
      for (int it = 0; it < 6; ++it) {
        const int g = it * 256 + t;
        const int pl = g >= 768;
        const int r = g - pl * 768;
        const int tp = r >> 8;
        const int rr = r & 255;
        const int co = rr >> 2;
        const int c16 = rr & 3;
        const ushort* src = (pl ? wl : wh) +
            ((((size_t)e * 3 + tp) * KC + kc) * CO + cb + co) * 32 + c16 * 8;
        gload_lds16(src, wsf + (size_t)g * 8);
      }
      __syncthreads();  // compiler drains vmcnt before s_barrier

      __builtin_amdgcn_s_setprio(1);
#pragma unroll
      for (int tp = 0; tp < 3; ++tp) {
        const int ar = wv * 32 + l16 + tp;
        s8v a00 = *reinterpret_cast<const s8v*>(&xs[0][ar][kb8]);
        s8v a01 = *reinterpret_cast<const s8v*>(&xs[0][ar + 16][kb8]);
        s8v a10 = *reinterpret_cast<const s8v*>(&xs[1][ar][kb8]);
        s8v a11 = *reinterpret_cast<const s8v*>(&xs[1][ar + 16][kb8]);
#pragma unroll
        for (int cs = 0; cs < 4; ++cs) {
          const int brow = cs * 16 + l16;
          s8v bh = *reinterpret_cast<const s8v*>(&wsm[0][tp][brow][kb8]);
          s8v bl = *reinterpret_cast<const s8v*>(&wsm[1][tp][brow][kb8]);
          acc[0][cs] = __builtin_amdgcn_mfma_f32_16x16x32_bf16(a00, bh, acc[0][cs], 0, 0, 0);
          acc[0][cs] = __builtin_amdgcn_mfma_f32_16x16x32_bf16(a00, bl, acc[0][cs], 0, 0, 0);
          acc[0][cs] = __builtin_amdgcn_mfma_f32_16x16x32_bf16(a10, bh, acc[0][cs], 0, 0, 0);
          acc[1][cs] = __builtin_amdgcn_mfma_f32_16x16x32_bf16(a01, bh, acc[1][cs], 0, 0, 0);
          acc[1][cs] = __builtin_amdgcn_mfma_f32_16x16x32_bf16(a01, bl, acc[1][cs], 0, 0, 0);
          acc[1][cs] = __builtin_amdgcn_mfma_f32_16x16x32_bf16(a11, bh, acc[1][cs], 0, 0, 0);
        }
      }
      __builtin_amdgcn_s_setprio(0);
      __syncthreads();
    }

#pragma unroll
    for (int cs = 0; cs < 4; ++cs)
      bv[cs] = bias[(size_t)e * CO + cb + cs * 16 + l16];

    if (OMODE == 1) {
#pragma unroll
      for (int ls = 0; ls < 2; ++ls)
#pragma unroll
        for (int cs = 0; cs < 4; ++cs)
#pragma unroll
          for (int q = 0; q < 2; ++q) {
            const float v0 = acc[ls][cs][q * 2] + bv[cs];
            const float v1 = acc[ls][cs][q * 2 + 1] + bv[cs];
            const float m = fmaxf(fmaxf(v0, v1), 0.f);
            gacc[ls][cs][q] += gate * m;
          }
    }
  }

  if (OMODE == 0) {
#pragma unroll
    for (int ls = 0; ls < 2; ++ls)
#pragma unroll
      for (int cs = 0; cs < 4; ++cs)
#pragma unroll
        for (int r = 0; r < 4; ++r) {
          const int l = lz + wv * 32 + ls * 16 + (lane >> 4) * 4 + r;
          const float v = acc[ls][cs][r] + bv[cs];
          const size_t o = ((size_t)lp * (L + 2) + 1 + l) * CO + cb + cs * 16 + l16;
          const ushort hi = f2bf(v);
          oh[o] = hi;
          ol[o] = f2bf(v - bf2f(hi));
        }
    if (blockIdx.z == 0 && t < 64) {
      const size_t o0 = (size_t)lp * (L + 2) * CO + cb + t;
      const size_t o1 = ((size_t)lp * (L + 2) + (L + 1)) * CO + cb + t;
      oh[o0] = 0; ol[o0] = 0; oh[o1] = 0; ol[o1] = 0;
    }
  } else if (OMODE == 3) {
#pragma unroll
    for (int ls = 0; ls < 2; ++ls)
#pragma unroll
      for (int cs = 0; cs < 4; ++cs)
#pragma unroll
        for (int r = 0; r < 4; r += 2) {
          const float v0 = acc[ls][cs][r] + bv[cs];
          const float v1 = acc[ls][cs][r + 1] + bv[cs];
          const float m = fmaxf(fmaxf(v0, v1), 0.f);
          const int lpp = (lz + wv * 32 + ls * 16 + (lane >> 4) * 4 + r) >> 1;
          const size_t o = ((size_t)lp * (L / 2 + 2) + 1 + lpp) * CO + cb + cs * 16 + l16;
          const ushort hi = f2bf(m);
          oh[o] = hi;
          ol[o] = f2bf(m - bf2f(hi));
        }
    if (blockIdx.z == 0 && t < 64) {
      const size_t o0 = (size_t)lp * (L / 2 + 2) * CO + cb + t;
      const size_t o1 = ((size_t)lp * (L / 2 + 2) + (L / 2 + 1)) * CO + cb + t;
      oh[o0] = 0; ol[o0] = 0; oh[o1] = 0; ol[o1] = 0;
    }
  } else if (OMODE == 1) {
    // gated sum -> bf16 hi/lo in [B][L/2+2][CO] halo layout (t2 fused)
#pragma unroll
    for (int ls = 0; ls < 2; ++ls)
#pragma unroll
      for (int cs = 0; cs < 4; ++cs)
#pragma unroll
        for (int q = 0; q < 2; ++q) {
          const int lpp = (lz + wv * 32 + ls * 16 + (lane >> 4) * 4 + q * 2) >> 1;
          const int co = cb + cs * 16 + l16;
          const size_t o =
              ((size_t)(pair0 + bx) * (L / 2 + 2) + 1 + lpp) * CO + co;
          const float g = gacc[ls][cs][q];
          const ushort hi = f2bf(g);
          oh[o] = hi;
          ol[o] = f2bf(g - bf2f(hi));
        }
    if (blockIdx.z == 0 && t < 64) {
      const size_t o0 = (size_t)(pair0 + bx) * (L / 2 + 2) * CO + cb + t;
      const size_t o1 =
          ((size_t)(pair0 + bx) * (L / 2 + 2) + (L / 2 + 1)) * CO + cb + t;
      oh[o0] = 0; ol[o0] = 0; oh[o1] = 0; ol[o1] = 0;
    }
  } else {
#pragma unroll
    for (int ls = 0; ls < 2; ++ls)
#pragma unroll
      for (int cs = 0; cs < 4; ++cs)
#pragma unroll
        for (int r = 0; r < 4; r += 2) {
          const float v0 = acc[ls][cs][r] + bv[cs];
          const float v1 = acc[ls][cs][r + 1] + bv[cs];
          const float m = fmaxf(fmaxf(v0, v1), 0.f);
          const int lpp = (lz + wv * 32 + ls * 16 + (lane >> 4) * 4 + r) >> 1;
          const int co = cb + cs * 16 + l16;
          const size_t o = ((size_t)lp * CO + co) * (L / 2) + lpp;
          of[o] = m;
        }
  }
}

// ---------------------------------------------------------------------------
// fc1 MFMA split-bf16 GEMM
// ---------------------------------------------------------------------------
__global__ __launch_bounds__(256) void fc1M_k(const float* __restrict__ X,
                                              const float* __restrict__ W,
                                              float* __restrict__ part)
{
  __shared__ ushort xs[2][128][32];
  __shared__ ushort wsm[2][64][32];
  const int t = threadIdx.x;
  const int lane = t & 63;
  const int wv = t >> 6;
  const int l16 = lane & 15;
  const int kb8 = (lane >> 4) * 8;
  const int ot = blockIdx.x * 64;
  const size_t k0g = (size_t)blockIdx.y * 512;

  f32x4 acc[2][4];
#pragma unroll
  for (int a = 0; a < 2; ++a)
#pragma unroll
    for (int b = 0; b < 4; ++b) acc[a][b] = (f32x4){0.f, 0.f, 0.f, 0.f};

  const int xrow = t >> 1;
  const int xcol = (t & 1) * 16;
  const int wco  = t >> 2;
  const int wk   = (t & 3) * 8;

  for (int it = 0; it < 16; ++it) {
    const size_t k0 = k0g + it * 32;
    {
      const float* src = X + (size_t)xrow * 65536 + k0 + xcol;
      float v[16];
#pragma unroll
      for (int q = 0; q < 4; ++q)
        *reinterpret_cast<float4*>(&v[q * 4]) =
            *reinterpret_cast<const float4*>(src + q * 4);
#pragma unroll
      for (int q = 0; q < 2; ++q) {
        u16x8 hv, lv;
#pragma unroll
        for (int j = 0; j < 8; ++j) {
          const float f = v[q * 8 + j];
          const ushort h = f2bf(f);
          hv[j] = h;
          lv[j] = f2bf(f - bf2f(h));
        }
        *reinterpret_cast<u16x8*>(&xs[0][xrow][xcol + q * 8]) = hv;
        *reinterpret_cast<u16x8*>(&xs[1][xrow][xcol + q * 8]) = lv;
      }
    }
    {
      const float* src = W + (size_t)(ot + wco) * 65536 + k0 + wk;
      float v[8];
      *reinterpret_cast<float4*>(&v[0]) = *reinterpret_cast<const float4*>(src);
      *reinterpret_cast<float4*>(&v[4]) = *reinterpret_cast<const float4*>(src + 4);
      u16x8 hv, lv;
#pragma unroll
      for (int j = 0; j < 8; ++j) {
        const ushort h = f2bf(v[j]);
        hv[j] = h;
        lv[j] = f2bf(v[j] - bf2f(h));
      }
      *reinterpret_cast<u16x8*>(&wsm[0][wco][wk]) = hv;
      *reinterpret_cast<u16x8*>(&wsm[1][wco][wk]) = lv;
    }
    __syncthreads();
    __builtin_amdgcn_s_setprio(1);
#pragma unroll
    for (int ms = 0; ms < 2; ++ms) {
      const int ar = wv * 32 + ms * 16 + l16;
      s8v ah = *reinterpret_cast<const s8v*>(&xs[0][ar][kb8]);
      s8v al = *reinterpret_cast<const s8v*>(&xs[1][ar][kb8]);
#pragma unroll
      for (int cs = 0; cs < 4; ++cs) {
        const int brow = cs * 16 + l16;
        s8v bh = *reinterpret_cast<const s8v*>(&wsm[0][brow][kb8]);
        s8v bl = *reinterpret_cast<const s8v*>(&wsm[1][brow][kb8]);
        acc[ms][cs] = __builtin_amdgcn_mfma_f32_16x16x32_bf16(ah, bh, acc[ms][cs], 0, 0, 0);
        acc[ms][cs] = __builtin_amdgcn_mfma_f32_16x16x32_bf16(ah, bl, acc[ms][cs], 0, 0, 0);
        acc[ms][cs] = __builtin_amdgcn_mfma_f32_16x16x32_bf16(al, bh, acc[ms][cs], 0, 0, 0);
      }
    }
    __builtin_amdgcn_s_setprio(0);
    __syncthreads();
  }

#pragma unroll
  for (int ms = 0; ms < 2; ++ms)
#pragma unroll
    for (int cs = 0; cs < 4; ++cs)
#pragma unroll
      for (int r = 0; r < 4; ++r) {
        const int row = wv * 32 + ms * 16 + (lane >> 4) * 4 + r;
        const int col = ot + cs * 16 + l16;
        part[((size_t)blockIdx.y * 128 + row) * 256 + col] = acc[ms][cs][r];
      }
}

__global__ void fc1red_k(const float* __restrict__ part,
                         const float* __restrict__ b1, float* __restrict__ o1)
{
  const int idx = blockIdx.x * 256 + threadIdx.x;
  if (idx < 32768) {
    float s = 0.f;
#pragma unroll 8
    for (int z = 0; z < 128; ++z) s += part[(size_t)z * 32768 + idx];
    o1[idx] = fmaxf(s + b1[idx & 255], 0.f);
  }
}

__global__ void fc2_k(const float* __restrict__ o1, const float* __restrict__ w2,
                      const float* __restrict__ b2, float* __restrict__ out)
{
  const int b = blockIdx.x;
  const int lane = threadIdx.x;
  float acc[5] = {0.f, 0.f, 0.f, 0.f, 0.f};
  for (int i = lane; i < 256; i += 64) {
    const float xv = o1[(size_t)b * 256 + i];
#pragma unroll
    for (int o = 0; o < 5; ++o) acc[o] = fmaf(xv, w2[o * 256 + i], acc[o]);
  }
#pragma unroll
  for (int o = 0; o < 5; ++o) {
    for (int off = 32; off > 0; off >>= 1)
      acc[o] += __shfl_down(acc[o], off, 64);
  }
  if (lane == 0) {
#pragma unroll
    for (int o = 0; o < 5; ++o) out[b * 5 + o] = acc[o] + b2[o];
  }
}

// ---------------------------------------------------------------------------
// launcher
// ---------------------------------------------------------------------------
extern "C" void kernel_launch(void* const* d_in, const int* in_sizes, int n_in,
                              void* d_out, int out_size, void* d_ws,
                              size_t ws_size, hipStream_t stream)
{
  const float* x   = (const float*)d_in[0];
  const float* c1w = (const float*)d_in[1];
  const float* c1b = (const float*)d_in[2];
  const float* ew[6];
  const float* eb[6];
  for (int j = 0; j < 6; ++j) {
    ew[j] = (const float*)d_in[3 + 2 * j];
    eb[j] = (const float*)d_in[4 + 2 * j];
  }
  const float* rw  = (const float*)d_in[15];
  const float* rb  = (const float*)d_in[16];
  const float* c2w = (const float*)d_in[17];
  const float* c2b = (const float*)d_in[18];
  const float* f1w = (const float*)d_in[19];
  const float* f1b = (const float*)d_in[20];
  const float* f2w = (const float*)d_in[21];
  const float* f2b = (const float*)d_in[22];
  float* out = (float*)d_out;

  const int chunkB = 32;
  const int chunkP = chunkB * 3;          // 96
  const int nchunk = 128 / chunkB;        // 4

  char* basep = (char*)d_ws;
  size_t off = 0;
  auto alloc = [&](size_t bytes) -> void* {
    off = (off + 255) & ~(size_t)255;
    void* r = basep + off;
    off += bytes;
    return r;
  };

  float* h      = (float*)alloc(2097152ull * 4);
  float* pooled = (float*)alloc(2048ull * 4);
  float* pairg  = (float*)alloc(384ull * 4);
  int*   paire  = (int*)  alloc(384ull * 4);
  float* fc1o   = (float*)alloc(32768ull * 4);

  // xtF: [128][130][512] hi/lo bf16 = 34.1 MB (part 16.8 MB aliases later)
  ushort* xtFh  = (ushort*)alloc(8519680ull * 2 * 2);
  ushort* xtFl  = xtFh + 8519680ull;
  float*  part  = (float*)xtFh;

  // chunk ping-pong slots; comb (33.5 MB) aliases slotA+slotB (38.0 MB)
  const size_t slot_base = (off + 255) & ~(size_t)255;
  char* slotA = (char*)alloc((size_t)chunkP * 33024 * 2 * 2);  // 12.7 MB
  char* slotB = (char*)alloc((size_t)chunkP * 66048 * 2 * 2);  // 25.4 MB
  float* comb = (float*)(basep + slot_base);

  float*  bufA  = (float*)slotA;
  ushort* xt3h  = (ushort*)slotA;
  ushort* xt3l  = xt3h + (size_t)chunkP * 16448;
  ushort* xt5h  = (ushort*)slotA;
  ushort* xt5l  = xt5h + (size_t)chunkP * 33024;
  float*  bufB  = (float*)slotB;
  ushort* yE3h  = (ushort*)slotB;
  ushort* yE3l  = yE3h + (size_t)chunkP * 32896;
  ushort* y5h   = (ushort*)slotB;
  ushort* y5l   = y5h + (size_t)chunkP * 66048;

  ushort* wp3h  = (ushort*)alloc(49152ull * 2);
  ushort* wp3l  = (ushort*)alloc(49152ull * 2);
  ushort* wp4h  = (ushort*)alloc(196608ull * 2);
  ushort* wp4l  = (ushort*)alloc(196608ull * 2);
  ushort* wp5h  = (ushort*)alloc(786432ull * 2);
  ushort* wp5l  = (ushort*)alloc(786432ull * 2);
  ushort* wp6h  = (ushort*)alloc(3145728ull * 2);
  ushort* wp6l  = (ushort*)alloc(3145728ull * 2);
  ushort* wpFh  = (ushort*)alloc(1572864ull * 2);
  ushort* wpFl  = (ushort*)alloc(1572864ull * 2);

  conv1_k<<<128, 256, 0, stream>>>(x, c1w, c1b, h, pooled);
  router_k<<<1, 128, 0, stream>>>(pooled, rw, rb, pairg, paire, out + 640);

  wprepAll_k<<<(5750784 + 255) / 256, 256, 0, stream>>>(
      ew[2], ew[3], ew[4], ew[5], c2w,
      wp3h, wp3l, wp4h, wp4l, wp5h, wp5l, wp6h, wp6l, wpFh, wpFl);

  for (int c = 0; c < nchunk; ++c) {
    const int b0 = c * chunkB;
    const int p0 = c * chunkP;
    convR_k<16, 16, 1024, false, 16, 16, 4, 3>
        <<<dim3(chunkP, 1, 4), 256, 0, stream>>>(
            h + (size_t)b0 * 16 * 1024, ew[0], eb[0], bufA, paire + p0);
    convR_k<16, 32, 1024, true, 16, 32, 8, 1>
        <<<dim3(chunkP, 1, 4), 256, 0, stream>>>(bufA, ew[1], eb[1], bufB,
                                                 paire + p0);
    t0_k<<<dim3(chunkP, 16), 256, 0, stream>>>(bufB, xt3h, xt3l);
    convM_k<32, 64, 512, 0>
        <<<dim3(chunkP, 1, 4), 256, 0, stream>>>(xt3h, xt3l, wp3h, wp3l, eb[2],
                                                 yE3h, yE3l, nullptr, paire,
                                                 nullptr, p0);
    convM_k<64, 128, 512, 3>
        <<<dim3(chunkP, 2, 4), 256, 0, stream>>>(yE3h, yE3l, wp4h, wp4l, eb[3],
                                                 xt5h, xt5l, nullptr, paire,
                                                 nullptr, p0);
    convM_k<128, 256, 256, 0>
        <<<dim3(chunkP, 4, 2), 256, 0, stream>>>(xt5h, xt5l, wp5h, wp5l, eb[4],
                                                 y5h, y5l, nullptr, paire,
                                                 nullptr, p0);
    // e6: 3 top-k pairs looped in-kernel, gated sum -> xtF bf16 (t2 fused)
    convM_k<256, 512, 256, 1>
        <<<dim3(chunkB, 8, 2), 256, 0, stream>>>(y5h, y5l, wp6h, wp6l, eb[5],
                                                 xtFh, xtFl, nullptr,
                                                 paire, pairg, b0);
  }

  convM_k<512, 1024, 128, 2>
      <<<dim3(128, 16, 1), 256, 0, stream>>>(xtFh, xtFl, wpFh, wpFl, c2b,
                                             nullptr, nullptr, comb, nullptr,
                                             nullptr, 0);

  fc1M_k<<<dim3(4, 128), 256, 0, stream>>>(comb, f1w, part);
  fc1red_k<<<128, 256, 0, stream>>>(part, f1b, fc1o);
  fc2_k<<<128, 64, 0, stream>>>(fc1o, f2w, f2b, out);
}

// Round 15
// 567.680 us; speedup vs baseline: 1.3216x; 1.1330x over previous
//
#include <hip/hip_runtime.h>
#include <hip/hip_bf16.h>
#include <math.h>

#define B_   128
#define L_   1024
#define E_   8
#define K_   3

typedef float f32x4 __attribute__((ext_vector_type(4)));
typedef short s8v  __attribute__((ext_vector_type(8)));
typedef unsigned short u16x8 __attribute__((ext_vector_type(8)));

__device__ inline ushort f2bf(float v) {
  union { float f; unsigned u; } x; x.f = v;
  unsigned r = (x.u + 0x7fffu + ((x.u >> 16) & 1u)) >> 16;
  return (ushort)r;
}
__device__ inline float bf2f(ushort h) {
  union { unsigned u; float f; } x; x.u = ((unsigned)h) << 16;
  return x.f;
}

// async global->LDS DMA, 16B/lane; dest linear in granule index.
__device__ __forceinline__ void gload_lds16(const ushort* g, ushort* l) {
  __builtin_amdgcn_global_load_lds(
      (const __attribute__((address_space(1))) unsigned int*)g,
      (__attribute__((address_space(3))) unsigned int*)l, 16, 0, 0);
}

// ---------------------------------------------------------------------------
// conv1: x[128,1,1024] -> h[128,16,1024] (ReLU) + pooled[128,16]
// ---------------------------------------------------------------------------
__global__ __launch_bounds__(256) void conv1_k(
    const float* __restrict__ x, const float* __restrict__ w,
    const float* __restrict__ bias, float* __restrict__ h,
    float* __restrict__ pooled)
{
  const int b = blockIdx.x;
  const int t = threadIdx.x;
  __shared__ float xs[1026];
  __shared__ float wsm[48];
  __shared__ float bs[16];
  __shared__ float red[4][16];

  for (int i = t; i < 1024; i += 256) xs[i + 1] = x[(size_t)b * 1024 + i];
  if (t == 0) { xs[0] = 0.f; xs[1025] = 0.f; }
  if (t < 48) wsm[t] = w[t];
  if (t < 16) bs[t] = bias[t];
  __syncthreads();

  float ps[16];
#pragma unroll
  for (int c = 0; c < 16; ++c) ps[c] = 0.f;

  for (int li = 0; li < 4; ++li) {
    const int l = t + li * 256;
    const float xm = xs[l], x0 = xs[l + 1], xp = xs[l + 2];
#pragma unroll
    for (int co = 0; co < 16; ++co) {
      float v = fmaf(wsm[co * 3 + 0], xm,
                fmaf(wsm[co * 3 + 1], x0,
                fmaf(wsm[co * 3 + 2], xp, bs[co])));
      v = fmaxf(v, 0.f);
      h[((size_t)b * 16 + co) * 1024 + l] = v;
      ps[co] += v;
    }
  }
#pragma unroll
  for (int co = 0; co < 16; ++co) {
    float v = ps[co];
    for (int off = 32; off > 0; off >>= 1) v += __shfl_down(v, off, 64);
    ps[co] = v;
  }
  const int wid = t >> 6, lane = t & 63;
  if (lane == 0) {
#pragma unroll
    for (int co = 0; co < 16; ++co) red[wid][co] = ps[co];
  }
  __syncthreads();
  if (t < 16) pooled[(size_t)b * 16 + t] =
      (red[0][t] + red[1][t] + red[2][t] + red[3][t]) * (1.f / 1024.f);
}

// ---------------------------------------------------------------------------
// router: pooled -> top3 gates + cv^2
// ---------------------------------------------------------------------------
__global__ void router_k(const float* __restrict__ pooled,
                         const float* __restrict__ rw,
                         const float* __restrict__ rb,
                         float* __restrict__ pair_g, int* __restrict__ pair_e,
                         float* __restrict__ cv2_out)
{
  const int b = threadIdx.x;  // 0..127
  __shared__ float pl[128][8];
  __shared__ float mp[8];

  float pv[16];
#pragma unroll
  for (int i = 0; i < 16; ++i) pv[i] = pooled[(size_t)b * 16 + i];

  float lg[8];
#pragma unroll
  for (int e = 0; e < 8; ++e) {
    float s = rb[e];
#pragma unroll
    for (int i = 0; i < 16; ++i) s = fmaf(pv[i], rw[e * 16 + i], s);
    lg[e] = s;
  }
  float mx = lg[0];
#pragma unroll
  for (int e = 1; e < 8; ++e) mx = fmaxf(mx, lg[e]);
  float pr[8]; float sum = 0.f;
#pragma unroll
  for (int e = 0; e < 8; ++e) { pr[e] = expf(lg[e] - mx); sum += pr[e]; }
  const float inv = 1.f / sum;
#pragma unroll
  for (int e = 0; e < 8; ++e) { pr[e] *= inv; pl[b][e] = pr[e]; }

  bool used[8] = {false,false,false,false,false,false,false,false};
  float tg[3]; int ti[3];
  for (int k = 0; k < 3; ++k) {
    float best = -1.f; int bi = 0;
#pragma unroll
    for (int e = 0; e < 8; ++e)
      if (!used[e] && pr[e] > best) { best = pr[e]; bi = e; }
    used[bi] = true; tg[k] = best; ti[k] = bi;
  }
  const float ts = 1.f / (tg[0] + tg[1] + tg[2]);
  for (int k = 0; k < 3; ++k) {
    pair_g[b * 3 + k] = tg[k] * ts;
    pair_e[b * 3 + k] = ti[k];
  }
  __syncthreads();
  if (b < 8) {
    float s = 0.f;
    for (int i = 0; i < 128; ++i) s += pl[i][b];
    mp[b] = s * (1.f / 128.f);
  }
  __syncthreads();
  if (b == 0) {
    float m = 0.f;
    for (int e = 0; e < 8; ++e) m += mp[e];
    m *= (1.f / 8.f);
    float v = 0.f;
    for (int e = 0; e < 8; ++e) { float d = mp[e] - m; v += d * d; }
    v *= (1.f / 7.f);
    const float cv = sqrtf(v) / (m + 1e-10f);
    cv2_out[0] = cv * cv;
  }
}

// ---------------------------------------------------------------------------
// Vector conv (e1, e2). TPOSE=true (e2): fused ReLU+pool and DIRECT bf16
// hi/lo store in e3's [P][LIN/2+2][CO] halo layout (t0 kernel fused away).
// ---------------------------------------------------------------------------
template <int CI, int CO, int LIN, bool POOL, int CIC, int CO_T, int CO_R,
          int IN_DIV, bool TPOSE>
__global__ __launch_bounds__(256) void convR_k(
    const float* __restrict__ in, const float* __restrict__ w,
    const float* __restrict__ bias, float* __restrict__ out,
    ushort* __restrict__ oh, ushort* __restrict__ ol,
    const int* __restrict__ pe)
{
  constexpr int CQ  = CO_T / CO_R;
  constexpr int LQ  = 256 / CQ;
  constexpr int L_T = LQ * 4;
  constexpr int LOUT = POOL ? (LIN / 2) : LIN;
  constexpr int RS  = L_T + 8;
  constexpr int CG  = CO_R / 4;

  const int p  = blockIdx.x;
  const int cb = blockIdx.y * CO_T;
  const int l0 = blockIdx.z * L_T;
  const int e  = pe ? pe[p] : 0;
  const float* inp = in + (size_t)(p / IN_DIV) * CI * LIN;
  const float* wp  = w + (size_t)e * CO * CI * 3;

  __shared__ float in_s[CIC * RS];
  __shared__ float w_s[CIC * 3 * CO_T];

  const int t  = threadIdx.x;
  const int cq = t / LQ;
  const int lq = t % LQ;

  float acc[CO_R][4];
#pragma unroll
  for (int c = 0; c < CO_R; ++c)
#pragma unroll
    for (int l = 0; l < 4; ++l) acc[c][l] = 0.f;

  for (int c0 = 0; c0 < CI; c0 += CIC) {
    for (int idx = t; idx < CIC * (L_T + 2); idx += 256) {
      const int ci = idx / (L_T + 2);
      const int j  = idx - ci * (L_T + 2);
      const int gl = l0 + j - 1;
      in_s[ci * RS + j] =
          (gl >= 0 && gl < LIN) ? inp[(size_t)(c0 + ci) * LIN + gl] : 0.f;
    }
    for (int i = t; i < CIC * CO_T; i += 256) {
      const int co = i % CO_T;
      const int ci = i / CO_T;
      const float* wsrc = wp + ((size_t)(cb + co) * CI + (c0 + ci)) * 3;
      const float w0 = wsrc[0], w1 = wsrc[1], w2 = wsrc[2];
      w_s[(ci * 3 + 0) * CO_T + co] = w0;
      w_s[(ci * 3 + 1) * CO_T + co] = w1;
      w_s[(ci * 3 + 2) * CO_T + co] = w2;
    }
    __syncthreads();
#pragma unroll 4
    for (int ci = 0; ci < CIC; ++ci) {
      const float* row = &in_s[ci * RS + lq * 4];
      const float4 xa = *reinterpret_cast<const float4*>(row);
      const float2 xb = *reinterpret_cast<const float2*>(row + 4);
      const float xv[6] = {xa.x, xa.y, xa.z, xa.w, xb.x, xb.y};
      const float* wrow = &w_s[ci * 3 * CO_T + cq * CO_R];
#pragma unroll
      for (int k = 0; k < 3; ++k) {
#pragma unroll
        for (int cg = 0; cg < CG; ++cg) {
          const float4 wv =
              *reinterpret_cast<const float4*>(&wrow[k * CO_T + cg * 4]);
          const float wq[4] = {wv.x, wv.y, wv.z, wv.w};
#pragma unroll
          for (int c = 0; c < 4; ++c)
#pragma unroll
            for (int l = 0; l < 4; ++l)
              acc[cg * 4 + c][l] = fmaf(wq[c], xv[l + k], acc[cg * 4 + c][l]);
        }
      }
    }
    __syncthreads();
  }

#pragma unroll
  for (int c = 0; c < CO_R; ++c) {
    const int co = cb + cq * CO_R + c;
    const float bv = bias[(size_t)e * CO + co];
    const float v0 = acc[c][0] + bv, v1 = acc[c][1] + bv;
    const float v2 = acc[c][2] + bv, v3 = acc[c][3] + bv;
    if (TPOSE) {
      // relu+pool, bf16 hi/lo in [P][LIN/2+2][CO] halo layout
      const float m0 = fmaxf(fmaxf(v0, v1), 0.f);
      const float m1 = fmaxf(fmaxf(v2, v3), 0.f);
      const int lo = (l0 >> 1) + lq * 2;
      const size_t o0 = ((size_t)p * (LIN / 2 + 2) + 1 + lo) * CO + co;
      const ushort h0 = f2bf(m0);
      oh[o0] = h0;
      ol[o0] = f2bf(m0 - bf2f(h0));
      const ushort h1 = f2bf(m1);
      oh[o0 + CO] = h1;
      ol[o0 + CO] = f2bf(m1 - bf2f(h1));
    } else {
      float* op = out + ((size_t)p * CO + co) * LOUT;
      if (POOL) {
        const int lo = (l0 >> 1) + lq * 2;
        float2 r;
        r.x = fmaxf(fmaxf(v0, v1), 0.f);
        r.y = fmaxf(fmaxf(v2, v3), 0.f);
        *reinterpret_cast<float2*>(&op[lo]) = r;
      } else {
        const int l = l0 + lq * 4;
        *reinterpret_cast<float4*>(&op[l]) = make_float4(v0, v1, v2, v3);
      }
    }
  }
  if (TPOSE) {
    if (blockIdx.z == 0 && t < CO) {
      const size_t o0 = (size_t)p * (LIN / 2 + 2) * CO + t;
      const size_t o1 = ((size_t)p * (LIN / 2 + 2) + (LIN / 2 + 1)) * CO + t;
      oh[o0] = 0; ol[o0] = 0; oh[o1] = 0; ol[o1] = 0;
    }
  }
}

// ---------------------------------------------------------------------------
// Merged weight prep: 5 segments, fp32 [E][CO][CI][3] -> hi/lo bf16
// [E][3][CI/32][CO][32]. One launch.
// ---------------------------------------------------------------------------
__global__ void wprepAll_k(const float* w3, const float* w4,
                           const float* w5, const float* w6,
                           const float* wF,
                           ushort* o3h, ushort* o3l, ushort* o4h, ushort* o4l,
                           ushort* o5h, ushort* o5l, ushort* o6h, ushort* o6l,
                           ushort* oFh, ushort* oFl)
{
  int idx = blockIdx.x * 256 + threadIdx.x;
  const float* w; ushort* oh; ushort* ol; int CO, CI;
  if (idx < 49152)        { w = w3; oh = o3h; ol = o3l; CO = 64;   CI = 32;  }
  else if (idx < 245760)  { idx -= 49152;
                            w = w4; oh = o4h; ol = o4l; CO = 128;  CI = 64;  }
  else if (idx < 1032192) { idx -= 245760;
                            w = w5; oh = o5h; ol = o5l; CO = 256;  CI = 128; }
  else if (idx < 4177920) { idx -= 1032192;
                            w = w6; oh = o6h; ol = o6l; CO = 512;  CI = 256; }
  else if (idx < 5750784) { idx -= 4177920;
                            w = wF; oh = oFh; ol = oFl; CO = 1024; CI = 512; }
  else return;

  const int KC = CI >> 5;
  const int j = idx & 31;
  int r = idx >> 5;
  const int co = r % CO; r /= CO;
  const int kc = r % KC; r /= KC;
  const int tp = r % 3;
  const int e  = r / 3;
  const float v = w[(((size_t)e * CO + co) * CI + (kc * 32 + j)) * 3 + tp];
  const ushort hi = f2bf(v);
  oh[idx] = hi;
  ol[idx] = f2bf(v - bf2f(hi));
}

// ---------------------------------------------------------------------------
// MFMA conv1d (k=3, pad=1), split-bf16 (hi/lo), 16x16x32 bf16 MFMA.
// X: [NP][L+2][CI] hi/lo bf16, W: [E][3][CI/32][CO][32]; BOTH staged to LDS
// via global_load_lds. Block: 256 thr = 4 waves stacked in l. Block tile:
// 128 l x 64 co. 41.2KB LDS -> 3 blocks/CU (proven optimum of this 2-barrier
// schedule).
// D: col=lane&15, row=(lane>>4)*4+reg (HW-verified layout).
// OMODE 0: plain conv -> bf16 hi/lo out [NP][L+2][CO] (halo zeroed)
// OMODE 1: relu+pool; loops the 3 top-k pairs of batch (pair0+bx) INTERNALLY,
//          gacc += gate*relu(pool(conv)); writes bf16 hi/lo in the next
//          conv's [B][L/2+2][CO] halo layout
// OMODE 2: relu+pool, fp32 transposed [NP][CO][L/2]
// OMODE 3: relu+pool -> bf16 hi/lo out [NP][L/2+2][CO] (halo zeroed)
// ---------------------------------------------------------------------------
template <int CI, int CO, int L, int OMODE>
__global__ __launch_bounds__(256) void convM_k(
    const ushort* __restrict__ xh, const ushort* __restrict__ xl,
    const ushort* __restrict__ wh, const ushort* __restrict__ wl,
    const float* __restrict__ bias,
    ushort* __restrict__ oh, ushort* __restrict__ ol,
    float* __restrict__ of,
    const int* __restrict__ pe, const float* __restrict__ pg,
    int pair0)
{
  constexpr int KC = CI / 32;
  constexpr int NK = (OMODE == 1) ? 3 : 1;
  const int bx = blockIdx.x;
  const int cb = blockIdx.y * 64;
  const int lz = blockIdx.z * 128;

  __shared__ ushort xs[2][130][32];
  __shared__ ushort wsm[2][3][64][32];
  ushort* xsf = &xs[0][0][0];
  ushort* wsf = &wsm[0][0][0][0];

  const int t = threadIdx.x;
  const int lane = t & 63;
  const int wv = t >> 6;
  const int l16 = lane & 15;
  const int kb8 = (lane >> 4) * 8;

  float gacc[2][4][2];
  if (OMODE == 1) {
#pragma unroll
    for (int a = 0; a < 2; ++a)
#pragma unroll
      for (int b = 0; b < 4; ++b) { gacc[a][b][0] = 0.f; gacc[a][b][1] = 0.f; }
  }

  f32x4 acc[2][4];
  int e = 0; float gate = 1.f; int lp = bx;
  float bv[4];

  for (int kp = 0; kp < NK; ++kp) {
    if (OMODE == 1) {
      const int gp = (pair0 + bx) * 3 + kp;  // pair0 = batch offset here
      e = pe[gp]; gate = pg[gp]; lp = bx * 3 + kp;
    } else if (OMODE == 2) { lp = bx; e = 0; }
    else { lp = bx; e = pe[pair0 + bx]; }

#pragma unroll
    for (int a = 0; a < 2; ++a)
#pragma unroll
      for (int b = 0; b < 4; ++b) acc[a][b] = (f32x4){0.f, 0.f, 0.f, 0.f};

    const size_t xbase = ((size_t)lp * (L + 2) + lz) * CI;

    for (int kc = 0; kc < KC; ++kc) {
      const int c0 = kc * 32;
      // X: 1040 granules (2 planes x 130 rows x 4), dest linear = xsf + g*8
#pragma unroll
      for (int it = 0; it < 5; ++it) {
        const int g = it * 256 + t;
        if (g < 1040) {
          const int pl = g >= 520;
          const int r = g - pl * 520;
          const int row = r >> 2;
          const int c16 = r & 3;
          const ushort* src =
              (pl ? xl : xh) + xbase + (size_t)row * CI + c0 + c16 * 8;
          gload_lds16(src, xsf + (size_t)g * 8);
        }
      }
      // W: 1536 granules (2 planes x 3 taps x 64 co x 4), dest = wsf + g*8
#pragma unroll
      for (int it = 0; it < 6; ++it) {
        const int g = it * 256 + t;
        const int pl = g >= 768;
        const int r = g - pl * 768;
        const int tp = r >> 8;
        const int rr = r & 255;
        const int co = rr >> 2;
        const int c16 = rr & 3;
        const ushort* src = (pl ? wl : wh) +
            ((((size_t)e * 3 + tp) * KC + kc) * CO + cb + co) * 32 + c16 * 8;
        gload_lds16(src, wsf + (size_t)g * 8);
      }
      __syncthreads();  // compiler drains vmcnt before s_barrier

      __builtin_amdgcn_s_setprio(1);
#pragma unroll
      for (int tp = 0; tp < 3; ++tp) {
        const int ar = wv * 32 + l16 + tp;
        s8v a00 = *reinterpret_cast<const s8v*>(&xs[0][ar][kb8]);
        s8v a01 = *reinterpret_cast<const s8v*>(&xs[0][ar + 16][kb8]);
        s8v a10 = *reinterpret_cast<const s8v*>(&xs[1][ar][kb8]);
        s8v a11 = *reinterpret_cast<const s8v*>(&xs[1][ar + 16][kb8]);
#pragma unroll
        for (int cs = 0; cs < 4; ++cs) {
          const int brow = cs * 16 + l16;
          s8v bh = *reinterpret_cast<const s8v*>(&wsm[0][tp][brow][kb8]);
          s8v bl = *reinterpret_cast<const s8v*>(&wsm[1][tp][brow][kb8]);
          acc[0][cs] = __builtin_amdgcn_mfma_f32_16x16x32_bf16(a00, bh, acc[0][cs], 0, 0, 0);
          acc[0][cs] = __builtin_amdgcn_mfma_f32_16x16x32_bf16(a00, bl, acc[0][cs], 0, 0, 0);
          acc[0][cs] = __builtin_amdgcn_mfma_f32_16x16x32_bf16(a10, bh, acc[0][cs], 0, 0, 0);
          acc[1][cs] = __builtin_amdgcn_mfma_f32_16x16x32_bf16(a01, bh, acc[1][cs], 0, 0, 0);
          acc[1][cs] = __builtin_amdgcn_mfma_f32_16x16x32_bf16(a01, bl, acc[1][cs], 0, 0, 0);
          acc[1][cs] = __builtin_amdgcn_mfma_f32_16x16x32_bf16(a11, bh, acc[1][cs], 0, 0, 0);
        }
      }
      __builtin_amdgcn_s_setprio(0);
      __syncthreads();
    }

#pragma unroll
    for (int cs = 0; cs < 4; ++cs)
      bv[cs] = bias[(size_t)e * CO + cb + cs * 16 + l16];

    if (OMODE == 1) {
#pragma unroll
      for (int ls = 0; ls < 2; ++ls)
#pragma unroll
        for (int cs = 0; cs < 4; ++cs)
#pragma unroll
          for (int q = 0; q < 2; ++q) {
            const float v0 = acc[ls][cs][q * 2] + bv[cs];
            const float v1 = acc[ls][cs][q * 2 + 1] + bv[cs];
            const float m = fmaxf(fmaxf(v0, v1), 0.f);
            gacc[ls][cs][q] += gate * m;
          }
    }
  }

  if (OMODE == 0) {
#pragma unroll
    for (int ls = 0; ls < 2; ++ls)
#pragma unroll
      for (int cs = 0; cs < 4; ++cs)
#pragma unroll
        for (int r = 0; r < 4; ++r) {
          const int l = lz + wv * 32 + ls * 16 + (lane >> 4) * 4 + r;
          const float v = acc[ls][cs][r] + bv[cs];
          const size_t o = ((size_t)lp * (L + 2) + 1 + l) * CO + cb + cs * 16 + l16;
          const ushort hi = f2bf(v);
          oh[o] = hi;
          ol[o] = f2bf(v - bf2f(hi));
        }
    if (blockIdx.z == 0 && t < 64) {
      const size_t o0 = (size_t)lp * (L + 2) * CO + cb + t;
      const size_t o1 = ((size_t)lp * (L + 2) + (L + 1)) * CO + cb + t;
      oh[o0] = 0; ol[o0] = 0; oh[o1] = 0; ol[o1] = 0;
    }
  } else if (OMODE == 3) {
#pragma unroll
    for (int ls = 0; ls < 2; ++ls)
#pragma unroll
      for (int cs = 0; cs < 4; ++cs)
#pragma unroll
        for (int r = 0; r < 4; r += 2) {
          const float v0 = acc[ls][cs][r] + bv[cs];
          const float v1 = acc[ls][cs][r + 1] + bv[cs];
          const float m = fmaxf(fmaxf(v0, v1), 0.f);
          const int lpp = (lz + wv * 32 + ls * 16 + (lane >> 4) * 4 + r) >> 1;
          const size_t o = ((size_t)lp * (L / 2 + 2) + 1 + lpp) * CO + cb + cs * 16 + l16;
          const ushort hi = f2bf(m);
          oh[o] = hi;
          ol[o] = f2bf(m - bf2f(hi));
        }
    if (blockIdx.z == 0 && t < 64) {
      const size_t o0 = (size_t)lp * (L / 2 + 2) * CO + cb + t;
      const size_t o1 = ((size_t)lp * (L / 2 + 2) + (L / 2 + 1)) * CO + cb + t;
      oh[o0] = 0; ol[o0] = 0; oh[o1] = 0; ol[o1] = 0;
    }
  } else if (OMODE == 1) {
    // gated sum -> bf16 hi/lo in [B][L/2+2][CO] halo layout (t2 fused)
#pragma unroll
    for (int ls = 0; ls < 2; ++ls)
#pragma unroll
      for (int cs = 0; cs < 4; ++cs)
#pragma unroll
        for (int q = 0; q < 2; ++q) {
          const int lpp = (lz + wv * 32 + ls * 16 + (lane >> 4) * 4 + q * 2) >> 1;
          const int co = cb + cs * 16 + l16;
          const size_t o =
              ((size_t)(pair0 + bx) * (L / 2 + 2) + 1 + lpp) * CO + co;
          const float g = gacc[ls][cs][q];
          const ushort hi = f2bf(g);
          oh[o] = hi;
          ol[o] = f2bf(g - bf2f(hi));
        }
    if (blockIdx.z == 0 && t < 64) {
      const size_t o0 = (size_t)(pair0 + bx) * (L / 2 + 2) * CO + cb + t;
      const size_t o1 =
          ((size_t)(pair0 + bx) * (L / 2 + 2) + (L / 2 + 1)) * CO + cb + t;
      oh[o0] = 0; ol[o0] = 0; oh[o1] = 0; ol[o1] = 0;
    }
  } else {
#pragma unroll
    for (int ls = 0; ls < 2; ++ls)
#pragma unroll
      for (int cs = 0; cs < 4; ++cs)
#pragma unroll
        for (int r = 0; r < 4; r += 2) {
          const float v0 = acc[ls][cs][r] + bv[cs];
          const float v1 = acc[ls][cs][r + 1] + bv[cs];
          const float m = fmaxf(fmaxf(v0, v1), 0.f);
          const int lpp = (lz + wv * 32 + ls * 16 + (lane >> 4) * 4 + r) >> 1;
          const int co = cb + cs * 16 + l16;
          const size_t o = ((size_t)lp * CO + co) * (L / 2) + lpp;
          of[o] = m;
        }
  }
}

// ---------------------------------------------------------------------------
// fc1 MFMA split-bf16 GEMM
// ---------------------------------------------------------------------------
__global__ __launch_bounds__(256) void fc1M_k(const float* __restrict__ X,
                                              const float* __restrict__ W,
                                              float* __restrict__ part)
{
  __shared__ ushort xs[2][128][32];
  __shared__ ushort wsm[2][64][32];
  const int t = threadIdx.x;
  const int lane = t & 63;
  const int wv = t >> 6;
  const int l16 = lane & 15;
  const int kb8 = (lane >> 4) * 8;
  const int ot = blockIdx.x * 64;
  const size_t k0g = (size_t)blockIdx.y * 512;

  f32x4 acc[2][4];
#pragma unroll
  for (int a = 0; a < 2; ++a)
#pragma unroll
    for (int b = 0; b < 4; ++b) acc[a][b] = (f32x4){0.f, 0.f, 0.f, 0.f};

  const int xrow = t >> 1;
  const int xcol = (t & 1) * 16;
  const int wco  = t >> 2;
  const int wk   = (t & 3) * 8;

  for (int it = 0; it < 16; ++it) {
    const size_t k0 = k0g + it * 32;
    {
      const float* src = X + (size_t)xrow * 65536 + k0 + xcol;
      float v[16];
#pragma unroll
      for (int q = 0; q < 4; ++q)
        *reinterpret_cast<float4*>(&v[q * 4]) =
            *reinterpret_cast<const float4*>(src + q * 4);
#pragma unroll
      for (int q = 0; q < 2; ++q) {
        u16x8 hv, lv;
#pragma unroll
        for (int j = 0; j < 8; ++j) {
          const float f = v[q * 8 + j];
          const ushort h = f2bf(f);
          hv[j] = h;
          lv[j] = f2bf(f - bf2f(h));
        }
        *reinterpret_cast<u16x8*>(&xs[0][xrow][xcol + q * 8]) = hv;
        *reinterpret_cast<u16x8*>(&xs[1][xrow][xcol + q * 8]) = lv;
      }
    }
    {
      const float* src = W + (size_t)(ot + wco) * 65536 + k0 + wk;
      float v[8];
      *reinterpret_cast<float4*>(&v[0]) = *reinterpret_cast<const float4*>(src);
      *reinterpret_cast<float4*>(&v[4]) = *reinterpret_cast<const float4*>(src + 4);
      u16x8 hv, lv;
#pragma unroll
      for (int j = 0; j < 8; ++j) {
        const ushort h = f2bf(v[j]);
        hv[j] = h;
        lv[j] = f2bf(v[j] - bf2f(h));
      }
      *reinterpret_cast<u16x8*>(&wsm[0][wco][wk]) = hv;
      *reinterpret_cast<u16x8*>(&wsm[1][wco][wk]) = lv;
    }
    __syncthreads();
    __builtin_amdgcn_s_setprio(1);
#pragma unroll
    for (int ms = 0; ms < 2; ++ms) {
      const int ar = wv * 32 + ms * 16 + l16;
      s8v ah = *reinterpret_cast<const s8v*>(&xs[0][ar][kb8]);
      s8v al = *reinterpret_cast<const s8v*>(&xs[1][ar][kb8]);
#pragma unroll
      for (int cs = 0; cs < 4; ++cs) {
        const int brow = cs * 16 + l16;
        s8v bh = *reinterpret_cast<const s8v*>(&wsm[0][brow][kb8]);
        s8v bl = *reinterpret_cast<const s8v*>(&wsm[1][brow][kb8]);
        acc[ms][cs] = __builtin_amdgcn_mfma_f32_16x16x32_bf16(ah, bh, acc[ms][cs], 0, 0, 0);
        acc[ms][cs] = __builtin_amdgcn_mfma_f32_16x16x32_bf16(ah, bl, acc[ms][cs], 0, 0, 0);
        acc[ms][cs] = __builtin_amdgcn_mfma_f32_16x16x32_bf16(al, bh, acc[ms][cs], 0, 0, 0);
      }
    }
    __builtin_amdgcn_s_setprio(0);
    __syncthreads();
  }

#pragma unroll
  for (int ms = 0; ms < 2; ++ms)
#pragma unroll
    for (int cs = 0; cs < 4; ++cs)
#pragma unroll
      for (int r = 0; r < 4; ++r) {
        const int row = wv * 32 + ms * 16 + (lane >> 4) * 4 + r;
        const int col = ot + cs * 16 + l16;
        part[((size_t)blockIdx.y * 128 + row) * 256 + col] = acc[ms][cs][r];
      }
}

__global__ void fc1red_k(const float* __restrict__ part,
                         const float* __restrict__ b1, float* __restrict__ o1)
{
  const int idx = blockIdx.x * 256 + threadIdx.x;
  if (idx < 32768) {
    float s = 0.f;
#pragma unroll 8
    for (int z = 0; z < 128; ++z) s += part[(size_t)z * 32768 + idx];
    o1[idx] = fmaxf(s + b1[idx & 255], 0.f);
  }
}

__global__ void fc2_k(const float* __restrict__ o1, const float* __restrict__ w2,
                      const float* __restrict__ b2, float* __restrict__ out)
{
  const int b = blockIdx.x;
  const int lane = threadIdx.x;
  float acc[5] = {0.f, 0.f, 0.f, 0.f, 0.f};
  for (int i = lane; i < 256; i += 64) {
    const float xv = o1[(size_t)b * 256 + i];
#pragma unroll
    for (int o = 0; o < 5; ++o) acc[o] = fmaf(xv, w2[o * 256 + i], acc[o]);
  }
#pragma unroll
  for (int o = 0; o < 5; ++o) {
    for (int off = 32; off > 0; off >>= 1)
      acc[o] += __shfl_down(acc[o], off, 64);
  }
  if (lane == 0) {
#pragma unroll
    for (int o = 0; o < 5; ++o) out[b * 5 + o] = acc[o] + b2[o];
  }
}

// ---------------------------------------------------------------------------
// launcher
// ---------------------------------------------------------------------------
extern "C" void kernel_launch(void* const* d_in, const int* in_sizes, int n_in,
                              void* d_out, int out_size, void* d_ws,
                              size_t ws_size, hipStream_t stream)
{
  const float* x   = (const float*)d_in[0];
  const float* c1w = (const float*)d_in[1];
  const float* c1b = (const float*)d_in[2];
  const float* ew[6];
  const float* eb[6];
  for (int j = 0; j < 6; ++j) {
    ew[j] = (const float*)d_in[3 + 2 * j];
    eb[j] = (const float*)d_in[4 + 2 * j];
  }
  const float* rw  = (const float*)d_in[15];
  const float* rb  = (const float*)d_in[16];
  const float* c2w = (const float*)d_in[17];
  const float* c2b = (const float*)d_in[18];
  const float* f1w = (const float*)d_in[19];
  const float* f1b = (const float*)d_in[20];
  const float* f2w = (const float*)d_in[21];
  const float* f2b = (const float*)d_in[22];
  float* out = (float*)d_out;

  // chunkB=32 plan totals ~98 MB (proven ws >= 127 MB). chunkB=64 (~143 MB)
  // only if the workspace clearly allows; it also lifts e6 to 4 blocks/CU.
  const int chunkB = (ws_size >= 160000000ull) ? 64 : 32;
  const int chunkP = chunkB * 3;
  const int nchunk = 128 / chunkB;

  char* basep = (char*)d_ws;
  size_t off = 0;
  auto alloc = [&](size_t bytes) -> void* {
    off = (off + 255) & ~(size_t)255;
    void* r = basep + off;
    off += bytes;
    return r;
  };

  float* h      = (float*)alloc(2097152ull * 4);
  float* pooled = (float*)alloc(2048ull * 4);
  float* pairg  = (float*)alloc(384ull * 4);
  int*   paire  = (int*)  alloc(384ull * 4);
  float* fc1o   = (float*)alloc(32768ull * 4);

  // xtF: [128][130][512] hi/lo bf16 = 34.1 MB (part 16.8 MB aliases later)
  ushort* xtFh  = (ushort*)alloc(8519680ull * 2 * 2);
  ushort* xtFl  = xtFh + 8519680ull;
  float*  part  = (float*)xtFh;

  // chunk ping-pong slots; comb (33.5 MB) aliases slotA+slotB
  const size_t slot_base = (off + 255) & ~(size_t)255;
  char* slotA = (char*)alloc((size_t)chunkP * 132096);  // bufA / xt5 hi+lo
  char* slotB = (char*)alloc((size_t)chunkP * 264192);  // yE3 / y5 hi+lo
  float* comb = (float*)(basep + slot_base);

  float*  bufA  = (float*)slotA;
  ushort* xt5h  = (ushort*)slotA;
  ushort* xt5l  = xt5h + (size_t)chunkP * 33024;
  ushort* yE3h  = (ushort*)slotB;
  ushort* yE3l  = yE3h + (size_t)chunkP * 32896;
  ushort* y5h   = (ushort*)slotB;
  ushort* y5l   = y5h + (size_t)chunkP * 66048;

  // dedicated xt3 (e2 writes it while reading bufA in slotA)
  ushort* xt3h  = (ushort*)alloc((size_t)chunkP * 16448 * 2 * 2);
  ushort* xt3l  = xt3h + (size_t)chunkP * 16448;

  ushort* wp3h  = (ushort*)alloc(49152ull * 2);
  ushort* wp3l  = (ushort*)alloc(49152ull * 2);
  ushort* wp4h  = (ushort*)alloc(196608ull * 2);
  ushort* wp4l  = (ushort*)alloc(196608ull * 2);
  ushort* wp5h  = (ushort*)alloc(786432ull * 2);
  ushort* wp5l  = (ushort*)alloc(786432ull * 2);
  ushort* wp6h  = (ushort*)alloc(3145728ull * 2);
  ushort* wp6l  = (ushort*)alloc(3145728ull * 2);
  ushort* wpFh  = (ushort*)alloc(1572864ull * 2);
  ushort* wpFl  = (ushort*)alloc(1572864ull * 2);

  conv1_k<<<128, 256, 0, stream>>>(x, c1w, c1b, h, pooled);
  router_k<<<1, 128, 0, stream>>>(pooled, rw, rb, pairg, paire, out + 640);

  wprepAll_k<<<(5750784 + 255) / 256, 256, 0, stream>>>(
      ew[2], ew[3], ew[4], ew[5], c2w,
      wp3h, wp3l, wp4h, wp4l, wp5h, wp5l, wp6h, wp6l, wpFh, wpFl);

  for (int c = 0; c < nchunk; ++c) {
    const int b0 = c * chunkB;
    const int p0 = c * chunkP;
    convR_k<16, 16, 1024, false, 16, 16, 4, 3, false>
        <<<dim3(chunkP, 1, 4), 256, 0, stream>>>(
            h + (size_t)b0 * 16 * 1024, ew[0], eb[0], bufA, nullptr, nullptr,
            paire + p0);
    // e2: relu+pool + direct bf16 hi/lo store in e3's halo layout (t0 fused)
    convR_k<16, 32, 1024, true, 16, 32, 8, 1, true>
        <<<dim3(chunkP, 1, 4), 256, 0, stream>>>(bufA, ew[1], eb[1], nullptr,
                                                 xt3h, xt3l, paire + p0);
    convM_k<32, 64, 512, 0>
        <<<dim3(chunkP, 1, 4), 256, 0, stream>>>(xt3h, xt3l, wp3h, wp3l, eb[2],
                                                 yE3h, yE3l, nullptr, paire,
                                                 nullptr, p0);
    convM_k<64, 128, 512, 3>
        <<<dim3(chunkP, 2, 4), 256, 0, stream>>>(yE3h, yE3l, wp4h, wp4l, eb[3],
                                                 xt5h, xt5l, nullptr, paire,
                                                 nullptr, p0);
    convM_k<128, 256, 256, 0>
        <<<dim3(chunkP, 4, 2), 256, 0, stream>>>(xt5h, xt5l, wp5h, wp5l, eb[4],
                                                 y5h, y5l, nullptr, paire,
                                                 nullptr, p0);
    // e6: 3 top-k pairs looped in-kernel, gated sum -> xtF bf16
    convM_k<256, 512, 256, 1>
        <<<dim3(chunkB, 8, 2), 256, 0, stream>>>(y5h, y5l, wp6h, wp6l, eb[5],
                                                 xtFh, xtFl, nullptr,
                                                 paire, pairg, b0);
  }

  convM_k<512, 1024, 128, 2>
      <<<dim3(128, 16, 1), 256, 0, stream>>>(xtFh, xtFl, wpFh, wpFl, c2b,
                                             nullptr, nullptr, comb, nullptr,
                                             nullptr, 0);

  fc1M_k<<<dim3(4, 128), 256, 0, stream>>>(comb, f1w, part);
  fc1red_k<<<128, 256, 0, stream>>>(part, f1b, fc1o);
  fc2_k<<<128, 64, 0, stream>>>(fc1o, f2w, f2b, out);
}